// Round 1
// 349.422 us; speedup vs baseline: 1.0861x; 1.0861x over previous
//
#include <hip/hip_runtime.h>
#include <stdint.h>

// ---------------- common helpers ----------------
typedef __attribute__((ext_vector_type(8))) short short8;
typedef __attribute__((ext_vector_type(4))) short short4v;
typedef __attribute__((ext_vector_type(4))) float float4v;
typedef __attribute__((ext_vector_type(8))) __bf16 bf16x8;

#define NCH 4  // attention S-dim split factor

__device__ __forceinline__ float4v mfma16x16x32(short8 a, short8 b, float4v c) {
  return __builtin_amdgcn_mfma_f32_16x16x32_bf16(
      __builtin_bit_cast(bf16x8, a), __builtin_bit_cast(bf16x8, b), c, 0, 0, 0);
}

// float -> bf16 (RNE), as raw short
__device__ __forceinline__ short f2bf(float f) {
  uint32_t u = __builtin_bit_cast(uint32_t, f);
  u += 0x7fffu + ((u >> 16) & 1u);
  return (short)(u >> 16);
}

__device__ __forceinline__ float bf2f(short s) {
  return __builtin_bit_cast(float, ((uint32_t)(uint16_t)s) << 16);
}

// async 16B global->LDS. LDS dst = wave-uniform base + lane*16 at all sites.
__device__ __forceinline__ void load_lds16(const short* g, short* l) {
  __builtin_amdgcn_global_load_lds(
      (const __attribute__((address_space(1))) void*)g,
      (__attribute__((address_space(3))) void*)l, 16, 0, 0);
}

// ---------------- fused fp32 -> bf16 for lang + 4 weights ----------------
__global__ __launch_bounds__(256) void convert5(
    const float* __restrict__ sl, short* __restrict__ dl,
    const float* __restrict__ s1, short* __restrict__ d1,
    const float* __restrict__ s2, short* __restrict__ d2,
    const float* __restrict__ s3, short* __restrict__ d3,
    const float* __restrict__ s4, short* __restrict__ d4) {
  const float* src; short* dst; int n4;
  switch (blockIdx.y) {
    case 0: src = sl; dst = dl; n4 = 131072; break;
    case 1: src = s1; dst = d1; n4 = 65536; break;
    case 2: src = s2; dst = d2; n4 = 65536; break;
    case 3: src = s3; dst = d3; n4 = 65536; break;
    default: src = s4; dst = d4; n4 = 65536; break;
  }
  const int stride = gridDim.x * blockDim.x;
  for (int i = blockIdx.x * blockDim.x + threadIdx.x; i < n4; i += stride) {
    float4v v = *(const float4v*)(src + (long)i * 4);
    short4v o;
#pragma unroll
    for (int r = 0; r < 4; r++) o[r] = f2bf(v[r]);
    *(short4v*)(dst + (long)i * 4) = o;
  }
}

// ---------------- small NT GEMM (q / out projections) ----------------
// C[m,n] = scale * sum_k A[m,k]*B[n,k]; 128x128 tile, BK=32, 4 waves.
// XOR-swizzled LDS. v2: double-buffered LDS + counted vmcnt + raw barriers —
// stage(t+2) issued while computing t, so the top-of-loop wait is vmcnt(4)
// (tile t landed, tile t+1 still in flight), never a full drain mid-loop.
template <int OUT_F32>
__global__ __launch_bounds__(256) void gemm_nt(
    const short* __restrict__ A, const short* __restrict__ B,
    void* __restrict__ C, int K, int ldc, float scale) {
  __shared__ alignas(16) short smem[16384];  // 2 x (lA 4096 | lB 4096) shorts
  const int tid = threadIdx.x;
  const int lane = tid & 63, w = tid >> 6;
  const int quad = lane >> 4, l16 = lane & 15;
  const int wm = w >> 1, wn = w & 1;
  const long m0 = (long)blockIdx.y * 128, n0 = (long)blockIdx.x * 128;

  float4v acc[4][4];
#pragma unroll
  for (int i = 0; i < 4; i++)
#pragma unroll
    for (int j = 0; j < 4; j++) acc[i][j] = (float4v)0.0f;

  const int srow = tid >> 2;  // 0..63 (also used at +64)
  const int scol = (((tid & 3) ^ ((srow >> 1) & 3))) * 8;  // swizzled source chunk
  const int nit = K >> 5;

#define STAGE_NT(t, base)                                                       \
  do {                                                                          \
    load_lds16(&A[(m0 + srow) * K + (t) * 32 + scol], &smem[(base) + tid * 8]); \
    load_lds16(&A[(m0 + 64 + srow) * K + (t) * 32 + scol],                      \
               &smem[(base) + 2048 + tid * 8]);                                 \
    load_lds16(&B[(n0 + srow) * K + (t) * 32 + scol],                           \
               &smem[(base) + 4096 + tid * 8]);                                 \
    load_lds16(&B[(n0 + 64 + srow) * K + (t) * 32 + scol],                      \
               &smem[(base) + 6144 + tid * 8]);                                 \
  } while (0)

  // prologue: stage tiles 0 and 1
  STAGE_NT(0, 0);
  if (nit > 1) STAGE_NT(1, 8192);

  for (int it = 0; it < nit; ++it) {
    const int base = (it & 1) * 8192;
    // tile it landed when <= 4 of my loads remain outstanding (tile it+1's)
    if (it + 1 < nit) asm volatile("s_waitcnt vmcnt(4)" ::: "memory");
    else              asm volatile("s_waitcnt vmcnt(0)" ::: "memory");
    __builtin_amdgcn_s_barrier();

    const short* lA = &smem[base];
    const short* lB = &smem[base + 4096];
    short8 af[4], bf[4];
#pragma unroll
    for (int t = 0; t < 4; t++) {
      const int ra = wm * 64 + t * 16 + l16;
      const int rb = wn * 64 + t * 16 + l16;
      af[t] = *(const short8*)&lA[ra * 32 + ((quad ^ ((ra >> 1) & 3)) * 8)];
      bf[t] = *(const short8*)&lB[rb * 32 + ((quad ^ ((rb >> 1) & 3)) * 8)];
    }
    asm volatile("s_waitcnt lgkmcnt(0)" ::: "memory");
    __builtin_amdgcn_sched_barrier(0);
    __builtin_amdgcn_s_barrier();  // all waves pulled tile it into regs

    if (it + 2 < nit) STAGE_NT(it + 2, base);  // overlaps MFMAs + next iter
#pragma unroll
    for (int i = 0; i < 4; i++)
#pragma unroll
      for (int j = 0; j < 4; j++)
        acc[i][j] = mfma16x16x32(af[i], bf[j], acc[i][j]);
  }
#undef STAGE_NT

  const int cm = wm * 64 + quad * 4;
  const int cn = wn * 64 + l16;
  if (OUT_F32) {
    float* Cf = (float*)C;
#pragma unroll
    for (int i = 0; i < 4; i++)
#pragma unroll
      for (int j = 0; j < 4; j++) {
        const long gn = n0 + cn + j * 16;
#pragma unroll
        for (int r = 0; r < 4; r++)
          Cf[(m0 + cm + i * 16 + r) * (long)ldc + gn] = acc[i][j][r] * scale;
      }
  } else {
    short* Cs = (short*)C;
#pragma unroll
    for (int i = 0; i < 4; i++)
#pragma unroll
      for (int j = 0; j < 4; j++) {
        const long gn = n0 + cn + j * 16;
#pragma unroll
        for (int r = 0; r < 4; r++)
          Cs[(m0 + cm + i * 16 + r) * (long)ldc + gn] = f2bf(acc[i][j][r] * scale);
      }
  }
}

// ---------------- fused KV projection ----------------
// k[s][i] (TRANS via LDS retile) and v[i][s] from shared visT tile.
// 512 threads = 8 waves: w0..3 -> k, w4..7 -> v. XOR-swizzled LDS.
// v2: double-buffered LDS (2 x 24 KB) + counted vmcnt + raw barriers.
// grid=(S/128, I/128, Bg).
__global__ __launch_bounds__(512) void gemm_kv(
    const short* __restrict__ Wk, const short* __restrict__ Wv,
    const short* __restrict__ visT, long sV,
    short* __restrict__ kout, short* __restrict__ vout, long sKV) {
  // 2 buffers x (lWk 4096 | lWv 4096 | lVis 4096) shorts = 48 KB.
  // epilogue scratch (8704 shorts) aliases buffer 0 (dead by then).
  __shared__ alignas(16) short smem[24576];
  const int tid = threadIdx.x;
  const int lane = tid & 63, w = tid >> 6;
  const int quad = lane >> 4, l16 = lane & 15;
  const int role = w >> 2;          // 0 = k, 1 = v
  const int wq = w & 3, wm = wq >> 1, wn = wq & 1;
  const long n0 = (long)blockIdx.x * 128;  // s
  const long m0 = (long)blockIdx.y * 128;  // i
  const short* vis = visT + blockIdx.z * sV;
  short* kz = kout + blockIdx.z * sKV;
  short* vz = vout + blockIdx.z * sKV;

  float4v acc[4][4];
#pragma unroll
  for (int i = 0; i < 4; i++)
#pragma unroll
    for (int j = 0; j < 4; j++) acc[i][j] = (float4v)0.0f;

  const int srow = tid >> 2;  // 0..127
  const int scol = (((tid & 3) ^ ((srow >> 1) & 3))) * 8;  // swizzled source chunk

  const short* gWk = &Wk[(m0 + srow) * 512 + scol];
  const short* gWv = &Wv[(m0 + srow) * 512 + scol];
  const short* gV = &vis[(n0 + srow) * 512 + scol];

#define STAGE_KV(t, base)                                      \
  do {                                                         \
    load_lds16(gWk + (t) * 32, &smem[(base) + tid * 8]);       \
    load_lds16(gWv + (t) * 32, &smem[(base) + 4096 + tid * 8]);\
    load_lds16(gV + (t) * 32, &smem[(base) + 8192 + tid * 8]); \
  } while (0)

  // prologue: stage tiles 0 and 1
  STAGE_KV(0, 0);
  STAGE_KV(1, 12288);

  for (int it = 0; it < 16; ++it) {
    const int base = (it & 1) * 12288;
    // tile it landed when <= 3 outstanding (tile it+1's own loads)
    if (it < 15) asm volatile("s_waitcnt vmcnt(3)" ::: "memory");
    else         asm volatile("s_waitcnt vmcnt(0)" ::: "memory");
    __builtin_amdgcn_s_barrier();

    const short* lW = &smem[base + (role ? 4096 : 0)];
    const short* lVis = &smem[base + 8192];
    short8 af[4], bf[4];
#pragma unroll
    for (int t = 0; t < 4; t++) {
      const int ra = wm * 64 + t * 16 + l16;
      const int rb = wn * 64 + t * 16 + l16;
      af[t] = *(const short8*)&lW[ra * 32 + ((quad ^ ((ra >> 1) & 3)) * 8)];
      bf[t] = *(const short8*)&lVis[rb * 32 + ((quad ^ ((rb >> 1) & 3)) * 8)];
    }
    asm volatile("s_waitcnt lgkmcnt(0)" ::: "memory");
    __builtin_amdgcn_sched_barrier(0);
    __builtin_amdgcn_s_barrier();  // all waves pulled tile it into regs

    if (it + 2 < 16) STAGE_KV(it + 2, base);  // overlaps MFMAs + next iter
#pragma unroll
    for (int i = 0; i < 4; i++)
#pragma unroll
      for (int j = 0; j < 4; j++)
        acc[i][j] = mfma16x16x32(af[i], bf[j], acc[i][j]);
  }
#undef STAGE_KV

  // C/D layout: col(n=s) = lane&15, row(m=i) = quad*4 + reg
  const int cm = wm * 64 + quad * 4;
  const int cn = wn * 64 + l16;

  // v: direct store (i,s)
  if (role == 1) {
#pragma unroll
    for (int i = 0; i < 4; i++)
#pragma unroll
      for (int j = 0; j < 4; j++) {
        const long gn = n0 + cn + j * 16;
#pragma unroll
        for (int r = 0; r < 4; r++)
          vz[(m0 + cm + i * 16 + r) * 4096 + gn] = f2bf(acc[i][j][r]);
      }
  }

  // k: retile through LDS -> coalesced 256B stores of k[s][i]
  short* scratch = smem;  // 64 rows x 136 shorts = 8704 <= 24576
#pragma unroll
  for (int h = 0; h < 2; h++) {
    __syncthreads();
    if (role == 0 && wn == h) {
#pragma unroll
      for (int j = 0; j < 4; j++)
#pragma unroll
        for (int i = 0; i < 4; i++) {
          const int nloc = j * 16 + l16;
          const int m = wm * 64 + i * 16 + quad * 4;
          short4v pk;
#pragma unroll
          for (int r = 0; r < 4; r++) pk[r] = f2bf(acc[i][j][r]);
          *(short4v*)&scratch[nloc * 136 + m] = pk;
        }
    }
    __syncthreads();
    {
      // drain full 64 x 128 tile: 512 threads x 16 shorts
      const int row = tid >> 3;        // 0..63
      const int off = (tid & 7) * 16;  // 0..112
      short8 v0 = *(const short8*)&scratch[row * 136 + off];
      short8 v1 = *(const short8*)&scratch[row * 136 + off + 8];
      *(short8*)&kz[(n0 + h * 64 + row) * 512 + m0 + off] = v0;
      *(short8*)&kz[(n0 + h * 64 + row) * 512 + m0 + off + 8] = v1;
    }
  }
}

// ---------------- vis fp32 (b,c,s) -> visT bf16 (b,s,c) ----------------
__global__ __launch_bounds__(256) void transpose_f2b(
    const float* __restrict__ vis, short* __restrict__ visT) {
  __shared__ alignas(16) short buf[64][68];
  const int tid = threadIdx.x;
  const long bz = blockIdx.z;
  const long s0 = (long)blockIdx.x * 64;
  const long c0 = (long)blockIdx.y * 64;
  const float* src = vis + bz * 512 * 4096;
  short* dst = visT + bz * 4096 * 512;
  const int tr = tid >> 4;
  const int tc4 = (tid & 15) * 4;
#pragma unroll
  for (int i = 0; i < 4; i++) {
    const int c = tr + i * 16;
    float4v val = *(const float4v*)&src[(c0 + c) * 4096 + s0 + tc4];
    buf[tc4 + 0][c] = f2bf(val[0]);
    buf[tc4 + 1][c] = f2bf(val[1]);
    buf[tc4 + 2][c] = f2bf(val[2]);
    buf[tc4 + 3][c] = f2bf(val[3]);
  }
  __syncthreads();
#pragma unroll
  for (int i = 0; i < 4; i++) {
    const int s = tr + i * 16;
    short4v val = *(const short4v*)&buf[s][tc4];
    *(short4v*)&dst[(s0 + s) * 512 + c0 + tc4] = val;
  }
}

// ---------------- attention partial: block = (head, batch, s-chunk) ----------------
// Each block covers 4096/NCH s-positions; no-max softmax partials.
// XOR-swizzled LDS; k/v fragment reads hoisted to registers so next chunk's
// staging overlaps QK -> softmax -> PV. v2: the "lp ready" barrier is a raw
// s_barrier + lgkmcnt(0) only — the next chunk's k/v staging stays in flight
// through PV (a __syncthreads here would emit vmcnt(0) and drain it).
__global__ __launch_bounds__(256) void attn_part(
    const short* __restrict__ q, const short* __restrict__ kws,
    const short* __restrict__ vws, float* __restrict__ Opart,
    float* __restrict__ lpart, int b0) {
  const int h = blockIdx.x;
  const int bz = blockIdx.y;
  const int ch = blockIdx.z;
  const int tid = threadIdx.x;
  const int lane = tid & 63, w = tid >> 6;
  const int quad = lane >> 4, l16 = lane & 15;

  __shared__ alignas(16) short lq[64 * 64];
  __shared__ alignas(16) short lk[128 * 64];
  __shared__ alignas(16) short lv[64 * 128];
  __shared__ alignas(16) short lp[64 * 128];
  __shared__ float lsum[64];

  const short* qb = q + ((long)(b0 + bz) * 64) * 512 + h * 64;
  const short* kb = kws + (long)bz * 4096 * 512 + h * 64;
  const short* vb = vws + (long)bz * 512 * 4096 + (long)h * 64 * 4096;

  if (tid < 64) lsum[tid] = 0.0f;
  {
    // lq: 64 rows x 8 chunks; slot (r, c) <- global chunk c ^ (r&7)
    const int qr = tid >> 3;
    const int qc = ((tid & 7) ^ (qr & 7)) * 8;
    load_lds16(&qb[qr * 512 + qc], &lq[tid * 8]);
    load_lds16(&qb[(32 + qr) * 512 + qc], &lq[2048 + tid * 8]);  // (32+qr)&7 == qr&7
  }
  // prologue: stage first k/v chunk (overlaps q fragment setup)
  const int s0_first = ch * (4096 / NCH);
  const int send = s0_first + (4096 / NCH);
#pragma unroll
  for (int it = 0; it < 4; it++) {
    const int li = tid + it * 256;
    const int kr = li >> 3;
    const int kc = ((li & 7) ^ (kr & 7)) * 8;
    load_lds16(&kb[(long)(s0_first + kr) * 512 + kc], &lk[li * 8]);
  }
#pragma unroll
  for (int it = 0; it < 4; it++) {
    const int li = tid + it * 256;
    const int vr = li >> 4;
    const int vc = ((li & 15) ^ (vr & 7)) * 8;
    load_lds16(&vb[(long)vr * 4096 + s0_first + vc], &lv[li * 8]);
  }
  __syncthreads();  // lq + first k/v landed

  short8 aq[4][2];
#pragma unroll
  for (int mt = 0; mt < 4; mt++)
#pragma unroll
    for (int ks = 0; ks < 2; ks++) {
      const int ra = mt * 16 + l16;
      aq[mt][ks] = *(const short8*)&lq[ra * 64 + (((ks * 4 + quad) ^ (ra & 7)) * 8)];
    }

  float4v osc[4];
#pragma unroll
  for (int mt = 0; mt < 4; mt++) osc[mt] = (float4v)0.0f;
  float lrow[4][4] = {};

  for (int s0 = s0_first; s0 < send; s0 += 128) {
    // pull ALL lk/lv fragments for this chunk into regs
    short8 bk[2][2];  // [ks][jn]
#pragma unroll
    for (int ks = 0; ks < 2; ks++)
#pragma unroll
      for (int jn = 0; jn < 2; jn++) {
        const int rb = (2 * w + jn) * 16 + l16;
        bk[ks][jn] = *(const short8*)&lk[rb * 64 + (((ks * 4 + quad) ^ (rb & 7)) * 8)];
      }
    short8 bv[4];
#pragma unroll
    for (int ks = 0; ks < 4; ks++) {
      const int rv = w * 16 + l16;
      bv[ks] = *(const short8*)&lv[rv * 128 + (((ks * 4 + quad) ^ (rv & 7)) * 8)];
    }
    __syncthreads();  // all waves done with lk/lv (also drains prior staging)

    if (s0 + 128 < send) {  // stage next chunk; overlaps QK+softmax+PV
#pragma unroll
      for (int it = 0; it < 4; it++) {
        const int li = tid + it * 256;
        const int kr = li >> 3;
        const int kc = ((li & 7) ^ (kr & 7)) * 8;
        load_lds16(&kb[(long)(s0 + 128 + kr) * 512 + kc], &lk[li * 8]);
      }
#pragma unroll
      for (int it = 0; it < 4; it++) {
        const int li = tid + it * 256;
        const int vr = li >> 4;
        const int vc = ((li & 15) ^ (vr & 7)) * 8;
        load_lds16(&vb[(long)vr * 4096 + s0 + 128 + vc], &lv[li * 8]);
      }
    }

    // scores: wave w covers s-tiles {2w, 2w+1}
    float4v sc[4][2];
#pragma unroll
    for (int mt = 0; mt < 4; mt++)
#pragma unroll
      for (int jn = 0; jn < 2; jn++) sc[mt][jn] = (float4v)0.0f;
#pragma unroll
    for (int ks = 0; ks < 2; ks++)
#pragma unroll
      for (int mt = 0; mt < 4; mt++)
#pragma unroll
        for (int jn = 0; jn < 2; jn++)
          sc[mt][jn] = mfma16x16x32(aq[mt][ks], bk[ks][jn], sc[mt][jn]);

    // p = exp(clamped score); bf16-quantized row sums; park p in lp (row-XOR).
#pragma unroll
    for (int mt = 0; mt < 4; mt++)
#pragma unroll
      for (int jn = 0; jn < 2; jn++)
#pragma unroll
        for (int r = 0; r < 4; r++) {
          const float scv = fminf(fmaxf(sc[mt][jn][r], -80.0f), 30.0f);
          const short sp = f2bf(__expf(scv));
          lrow[mt][r] += bf2f(sp);
          const int rowp = mt * 16 + quad * 4 + r;
          const int col = (2 * w + jn) * 16 + l16;
          lp[rowp * 128 + (((col >> 3) ^ (rowp & 7)) * 8) + (col & 7)] = sp;
        }
    // lp ready: raw barrier — k/v staging must STAY in flight through PV
    asm volatile("s_waitcnt lgkmcnt(0)" ::: "memory");
    __builtin_amdgcn_sched_barrier(0);
    __builtin_amdgcn_s_barrier();

    // PV from lp (this-iter data) and bv regs
#pragma unroll
    for (int ks = 0; ks < 4; ks++)
#pragma unroll
      for (int mt = 0; mt < 4; mt++) {
        const int rp = mt * 16 + l16;
        const short8 ap = *(const short8*)&lp[rp * 128 + (((ks * 4 + quad) ^ (rp & 7)) * 8)];
        osc[mt] = mfma16x16x32(ap, bv[ks], osc[mt]);
      }
    __syncthreads();  // everyone done with lp; staging drains before next frag reads
  }

#pragma unroll
  for (int mt = 0; mt < 4; mt++)
#pragma unroll
    for (int r = 0; r < 4; r++) {
      float v = lrow[mt][r];
      v += __shfl_xor(v, 1);
      v += __shfl_xor(v, 2);
      v += __shfl_xor(v, 4);
      v += __shfl_xor(v, 8);
      if (l16 == 0) atomicAdd(&lsum[mt * 16 + quad * 4 + r], v);
    }
  __syncthreads();

  const long bh = bz * 8 + h;
  float* op = Opart + ((bh * NCH + ch) * 64) * 64 + w * 16 + l16;
#pragma unroll
  for (int mt = 0; mt < 4; mt++)
#pragma unroll
    for (int r = 0; r < 4; r++)
      op[(long)(mt * 16 + quad * 4 + r) * 64] = osc[mt][r];
  if (tid < 64) lpart[(bh * NCH + ch) * 64 + tid] = lsum[tid];
}

// ---------------- combine attention partials -> tmp bf16 (b,t,i) ----------------
__global__ __launch_bounds__(256) void attn_combine(
    const float* __restrict__ Opart, const float* __restrict__ lpart,
    short* __restrict__ tmp, int b0, int nbh) {
  const int total = nbh * 4096;
  for (int idx = blockIdx.x * 256 + threadIdx.x; idx < total;
       idx += gridDim.x * 256) {
    const int bh = idx >> 12;
    const int td = idx & 4095;
    const int t = td >> 6, d = td & 63;
    float o = 0.0f, l = 0.0f;
#pragma unroll
    for (int c = 0; c < NCH; c++) {
      o += Opart[((long)bh * NCH + c) * 4096 + td];
      l += lpart[(bh * NCH + c) * 64 + t];
    }
    const int b = b0 + (bh >> 3), h = bh & 7;
    tmp[((long)b * 64 + t) * 512 + h * 64 + d] = f2bf(o / l);
  }
}

// ---------------- launch ----------------
extern "C" void kernel_launch(void* const* d_in, const int* in_sizes, int n_in,
                              void* d_out, int out_size, void* d_ws, size_t ws_size,
                              hipStream_t stream) {
  (void)in_sizes; (void)n_in; (void)out_size;
  const float* vis = (const float*)d_in[0];   // [16][512][4096] fp32
  const float* lang = (const float*)d_in[1];  // [16][64][512]  fp32
  const float* Wq = (const float*)d_in[3];    // [512][512] fp32
  const float* Wk = (const float*)d_in[4];
  const float* Wv = (const float*)d_in[5];
  const float* Wo = (const float*)d_in[6];
  float* out = (float*)d_out;                 // [16][64][512] fp32

  char* ws = (char*)d_ws;
  const size_t MB = 1 << 20;
  short* q_ws = (short*)(ws + 0 * MB);
  short* tmp_ws = (short*)(ws + 1 * MB);
  short* langb = (short*)(ws + 2 * MB);
  short* Wqb = (short*)(ws + 3 * MB);
  short* Wkb = (short*)(ws + 3 * MB + 512 * 1024);
  short* Wvb = (short*)(ws + 4 * MB);
  short* Wob = (short*)(ws + 4 * MB + 512 * 1024);
  char* grp = ws + 5 * MB;

  const long batch_elems = 4096l * 512;
  int g = 16;
  const int cands[5] = {1, 2, 4, 8, 16};
  for (int ci = 0; ci < 5; ci++) {
    const size_t need = 5 * MB + 3ull * (16 / cands[ci]) * batch_elems * 2;
    if (need <= ws_size) { g = cands[ci]; break; }
  }
  const int Bg = 16 / g;
  short* visT = (short*)grp;                    // [Bg][4096][512]
  short* k_ws = visT + (long)Bg * batch_elems;  // [Bg][4096][512] (s,i)
  short* v_ws = k_ws + (long)Bg * batch_elems;  // [Bg][512][4096] (i,s)
  // attn partials alias visT (dead by attn time)
  float* Opart = (float*)visT;
  float* lptr = Opart + (long)Bg * 8 * NCH * 4096;

  convert5<<<dim3(128, 5), 256, 0, stream>>>(lang, langb, Wq, Wqb, Wk, Wkb,
                                             Wv, Wvb, Wo, Wob);

  // q = SCALE * lang @ Wq^T
  gemm_nt<0><<<dim3(4, 8), 256, 0, stream>>>(langb, Wqb, q_ws, 512, 512, 0.125f);

  for (int gi = 0; gi < g; gi++) {
    const int b0 = gi * Bg;
    transpose_f2b<<<dim3(64, 8, Bg), 256, 0, stream>>>(vis + (long)b0 * batch_elems, visT);
    gemm_kv<<<dim3(32, 4, Bg), 512, 0, stream>>>(Wkb, Wvb, visT, batch_elems,
                                                 k_ws, v_ws, batch_elems);
    attn_part<<<dim3(8, Bg, NCH), 256, 0, stream>>>(q_ws, k_ws, v_ws, Opart, lptr, b0);
    attn_combine<<<512, 256, 0, stream>>>(Opart, lptr, tmp_ws, b0, Bg * 8);
  }

  // out = tmp @ Wo^T, fp32 epilogue
  gemm_nt<1><<<dim3(4, 8), 256, 0, stream>>>(tmp_ws, Wob, out, 512, 512, 1.0f);
}

// Round 2
// 340.803 us; speedup vs baseline: 1.1136x; 1.0253x over previous
//
#include <hip/hip_runtime.h>
#include <stdint.h>

// ---------------- common helpers ----------------
typedef __attribute__((ext_vector_type(8))) short short8;
typedef __attribute__((ext_vector_type(4))) short short4v;
typedef __attribute__((ext_vector_type(4))) float float4v;
typedef __attribute__((ext_vector_type(8))) __bf16 bf16x8;

#define NCH 4  // attention S-dim split factor

__device__ __forceinline__ float4v mfma16x16x32(short8 a, short8 b, float4v c) {
  return __builtin_amdgcn_mfma_f32_16x16x32_bf16(
      __builtin_bit_cast(bf16x8, a), __builtin_bit_cast(bf16x8, b), c, 0, 0, 0);
}

// float -> bf16 (RNE), as raw short
__device__ __forceinline__ short f2bf(float f) {
  uint32_t u = __builtin_bit_cast(uint32_t, f);
  u += 0x7fffu + ((u >> 16) & 1u);
  return (short)(u >> 16);
}

__device__ __forceinline__ float bf2f(short s) {
  return __builtin_bit_cast(float, ((uint32_t)(uint16_t)s) << 16);
}

// async 16B global->LDS. LDS dst = wave-uniform base + lane*16 at all sites.
__device__ __forceinline__ void load_lds16(const short* g, short* l) {
  __builtin_amdgcn_global_load_lds(
      (const __attribute__((address_space(1))) void*)g,
      (__attribute__((address_space(3))) void*)l, 16, 0, 0);
}

// ---------------- fused fp32 -> bf16 for lang + 4 weights ----------------
__global__ __launch_bounds__(256) void convert5(
    const float* __restrict__ sl, short* __restrict__ dl,
    const float* __restrict__ s1, short* __restrict__ d1,
    const float* __restrict__ s2, short* __restrict__ d2,
    const float* __restrict__ s3, short* __restrict__ d3,
    const float* __restrict__ s4, short* __restrict__ d4) {
  const float* src; short* dst; int n4;
  switch (blockIdx.y) {
    case 0: src = sl; dst = dl; n4 = 131072; break;
    case 1: src = s1; dst = d1; n4 = 65536; break;
    case 2: src = s2; dst = d2; n4 = 65536; break;
    case 3: src = s3; dst = d3; n4 = 65536; break;
    default: src = s4; dst = d4; n4 = 65536; break;
  }
  const int stride = gridDim.x * blockDim.x;
  for (int i = blockIdx.x * blockDim.x + threadIdx.x; i < n4; i += stride) {
    float4v v = *(const float4v*)(src + (long)i * 4);
    short4v o;
#pragma unroll
    for (int r = 0; r < 4; r++) o[r] = f2bf(v[r]);
    *(short4v*)(dst + (long)i * 4) = o;
  }
}

// ---------------- small NT GEMM (q / out projections) ----------------
// C[m,n] = scale * sum_k A[m,k]*B[n,k]; 128x128 tile, BK=32, 4 waves.
// XOR-swizzled LDS; double-buffered LDS + counted vmcnt + raw barriers.
template <int OUT_F32>
__global__ __launch_bounds__(256) void gemm_nt(
    const short* __restrict__ A, const short* __restrict__ B,
    void* __restrict__ C, int K, int ldc, float scale) {
  __shared__ alignas(16) short smem[16384];  // 2 x (lA 4096 | lB 4096) shorts
  const int tid = threadIdx.x;
  const int lane = tid & 63, w = tid >> 6;
  const int quad = lane >> 4, l16 = lane & 15;
  const int wm = w >> 1, wn = w & 1;
  const long m0 = (long)blockIdx.y * 128, n0 = (long)blockIdx.x * 128;

  float4v acc[4][4];
#pragma unroll
  for (int i = 0; i < 4; i++)
#pragma unroll
    for (int j = 0; j < 4; j++) acc[i][j] = (float4v)0.0f;

  const int srow = tid >> 2;  // 0..63 (also used at +64)
  const int scol = (((tid & 3) ^ ((srow >> 1) & 3))) * 8;  // swizzled source chunk
  const int nit = K >> 5;

#define STAGE_NT(t, base)                                                       \
  do {                                                                          \
    load_lds16(&A[(m0 + srow) * K + (t) * 32 + scol], &smem[(base) + tid * 8]); \
    load_lds16(&A[(m0 + 64 + srow) * K + (t) * 32 + scol],                      \
               &smem[(base) + 2048 + tid * 8]);                                 \
    load_lds16(&B[(n0 + srow) * K + (t) * 32 + scol],                           \
               &smem[(base) + 4096 + tid * 8]);                                 \
    load_lds16(&B[(n0 + 64 + srow) * K + (t) * 32 + scol],                      \
               &smem[(base) + 6144 + tid * 8]);                                 \
  } while (0)

  // prologue: stage tiles 0 and 1
  STAGE_NT(0, 0);
  if (nit > 1) STAGE_NT(1, 8192);

  for (int it = 0; it < nit; ++it) {
    const int base = (it & 1) * 8192;
    // tile it landed when <= 4 of my loads remain outstanding (tile it+1's)
    if (it + 1 < nit) asm volatile("s_waitcnt vmcnt(4)" ::: "memory");
    else              asm volatile("s_waitcnt vmcnt(0)" ::: "memory");
    __builtin_amdgcn_s_barrier();

    const short* lA = &smem[base];
    const short* lB = &smem[base + 4096];
    short8 af[4], bf[4];
#pragma unroll
    for (int t = 0; t < 4; t++) {
      const int ra = wm * 64 + t * 16 + l16;
      const int rb = wn * 64 + t * 16 + l16;
      af[t] = *(const short8*)&lA[ra * 32 + ((quad ^ ((ra >> 1) & 3)) * 8)];
      bf[t] = *(const short8*)&lB[rb * 32 + ((quad ^ ((rb >> 1) & 3)) * 8)];
    }
    asm volatile("s_waitcnt lgkmcnt(0)" ::: "memory");
    __builtin_amdgcn_sched_barrier(0);
    __builtin_amdgcn_s_barrier();  // all waves pulled tile it into regs

    if (it + 2 < nit) STAGE_NT(it + 2, base);  // overlaps MFMAs + next iter
#pragma unroll
    for (int i = 0; i < 4; i++)
#pragma unroll
      for (int j = 0; j < 4; j++)
        acc[i][j] = mfma16x16x32(af[i], bf[j], acc[i][j]);
  }
#undef STAGE_NT

  const int cm = wm * 64 + quad * 4;
  const int cn = wn * 64 + l16;
  if (OUT_F32) {
    float* Cf = (float*)C;
#pragma unroll
    for (int i = 0; i < 4; i++)
#pragma unroll
      for (int j = 0; j < 4; j++) {
        const long gn = n0 + cn + j * 16;
#pragma unroll
        for (int r = 0; r < 4; r++)
          Cf[(m0 + cm + i * 16 + r) * (long)ldc + gn] = acc[i][j][r] * scale;
      }
  } else {
    short* Cs = (short*)C;
#pragma unroll
    for (int i = 0; i < 4; i++)
#pragma unroll
      for (int j = 0; j < 4; j++) {
        const long gn = n0 + cn + j * 16;
#pragma unroll
        for (int r = 0; r < 4; r++)
          Cs[(m0 + cm + i * 16 + r) * (long)ldc + gn] = f2bf(acc[i][j][r] * scale);
      }
  }
}

// ---------------- fused KV projection ----------------
// v3: k+v FUSED PER WAVE — the old 8-wave role split had k-waves and v-waves
// reading identical lVis fragments (every vis byte crossed the LDS read port
// twice; kernel was LDS-pipe-bound at MfmaUtil 29%). Now 4 waves, each wave
// reads ak[4](Wk) + av[4](Wv) + bf[4](vis) = 12 ds_read_b128 and issues
// 32 MFMAs (16 k + 16 v): reads/MFMA 0.5 -> 0.375. Same 128x128 k and v
// output tiles per block, same grid, 256 threads.
// Double-buffered LDS (2 x 24 KB) + counted vmcnt + raw barriers.
// grid=(S/128, I/128, Bg).
__global__ __launch_bounds__(256, 2) void gemm_kv(
    const short* __restrict__ Wk, const short* __restrict__ Wv,
    const short* __restrict__ visT, long sV,
    short* __restrict__ kout, short* __restrict__ vout, long sKV) {
  // 2 buffers x (lWk 4096 | lWv 4096 | lVis 4096) shorts = 48 KB.
  // epilogue scratch (8704 shorts) aliases buffer 0 (dead by then).
  __shared__ alignas(16) short smem[24576];
  const int tid = threadIdx.x;
  const int lane = tid & 63, w = tid >> 6;  // w 0..3
  const int quad = lane >> 4, l16 = lane & 15;
  const int wm = w >> 1, wn = w & 1;
  const long n0 = (long)blockIdx.x * 128;  // s
  const long m0 = (long)blockIdx.y * 128;  // i
  const short* vis = visT + blockIdx.z * sV;
  short* kz = kout + blockIdx.z * sKV;
  short* vz = vout + blockIdx.z * sKV;

  float4v acck[4][4], accv[4][4];
#pragma unroll
  for (int i = 0; i < 4; i++)
#pragma unroll
    for (int j = 0; j < 4; j++) {
      acck[i][j] = (float4v)0.0f;
      accv[i][j] = (float4v)0.0f;
    }

  // staging: each 128x32 tile = 512 16B-chunks; thread covers chunks tid and
  // tid+256 (same swizzle map as the old 512-thread version, li = old tid).
  const int sr0 = tid >> 2, sc0 = (((tid & 3) ^ ((sr0 >> 1) & 3))) * 8;
  const int li1 = tid + 256;
  const int sr1 = li1 >> 2, sc1 = (((li1 & 3) ^ ((sr1 >> 1) & 3))) * 8;
  const short* gWk0 = &Wk[(m0 + sr0) * 512 + sc0];
  const short* gWk1 = &Wk[(m0 + sr1) * 512 + sc1];
  const short* gWv0 = &Wv[(m0 + sr0) * 512 + sc0];
  const short* gWv1 = &Wv[(m0 + sr1) * 512 + sc1];
  const short* gV0 = &vis[(n0 + sr0) * 512 + sc0];
  const short* gV1 = &vis[(n0 + sr1) * 512 + sc1];

#define STAGE_KV(t, base)                                         \
  do {                                                            \
    load_lds16(gWk0 + (t) * 32, &smem[(base) + tid * 8]);         \
    load_lds16(gWk1 + (t) * 32, &smem[(base) + 2048 + tid * 8]);  \
    load_lds16(gWv0 + (t) * 32, &smem[(base) + 4096 + tid * 8]);  \
    load_lds16(gWv1 + (t) * 32, &smem[(base) + 6144 + tid * 8]);  \
    load_lds16(gV0 + (t) * 32, &smem[(base) + 8192 + tid * 8]);   \
    load_lds16(gV1 + (t) * 32, &smem[(base) + 10240 + tid * 8]);  \
  } while (0)

  // prologue: stage tiles 0 and 1
  STAGE_KV(0, 0);
  STAGE_KV(1, 12288);

  for (int it = 0; it < 16; ++it) {
    const int base = (it & 1) * 12288;
    // tile it landed when <= 6 outstanding (tile it+1's own loads)
    if (it < 15) asm volatile("s_waitcnt vmcnt(6)" ::: "memory");
    else         asm volatile("s_waitcnt vmcnt(0)" ::: "memory");
    __builtin_amdgcn_s_barrier();

    const short* lWk_ = &smem[base];
    const short* lWv_ = &smem[base + 4096];
    const short* lV_ = &smem[base + 8192];
    short8 ak[4], av[4], bfv[4];
#pragma unroll
    for (int t = 0; t < 4; t++) {
      const int ra = wm * 64 + t * 16 + l16;
      const int rb = wn * 64 + t * 16 + l16;
      const int oa = ra * 32 + ((quad ^ ((ra >> 1) & 3)) * 8);
      const int ob = rb * 32 + ((quad ^ ((rb >> 1) & 3)) * 8);
      ak[t] = *(const short8*)&lWk_[oa];
      av[t] = *(const short8*)&lWv_[oa];
      bfv[t] = *(const short8*)&lV_[ob];
    }
    asm volatile("s_waitcnt lgkmcnt(0)" ::: "memory");
    __builtin_amdgcn_sched_barrier(0);
    __builtin_amdgcn_s_barrier();  // all waves pulled tile it into regs

    if (it + 2 < 16) STAGE_KV(it + 2, base);  // overlaps MFMAs + next iter
#pragma unroll
    for (int i = 0; i < 4; i++)
#pragma unroll
      for (int j = 0; j < 4; j++) {
        acck[i][j] = mfma16x16x32(ak[i], bfv[j], acck[i][j]);
        accv[i][j] = mfma16x16x32(av[i], bfv[j], accv[i][j]);
      }
  }
#undef STAGE_KV

  // C/D layout: col(n=s) = lane&15, row(m=i) = quad*4 + reg
  const int cm = wm * 64 + quad * 4;
  const int cn = wn * 64 + l16;

  // v: direct store (i,s) — every wave stores its 64x64 v tile
#pragma unroll
  for (int i = 0; i < 4; i++)
#pragma unroll
    for (int j = 0; j < 4; j++) {
      const long gn = n0 + cn + j * 16;
#pragma unroll
      for (int r = 0; r < 4; r++)
        vz[(m0 + cm + i * 16 + r) * 4096 + gn] = f2bf(accv[i][j][r]);
    }

  // k: retile through LDS -> coalesced 256B stores of k[s][i]
  short* scratch = smem;  // 64 rows x 136 shorts = 8704 <= 24576
#pragma unroll
  for (int h = 0; h < 2; h++) {
    __syncthreads();
    if (wn == h) {  // 2 waves (wm=0,1) cover the full 64(n) x 128(m) tile
#pragma unroll
      for (int j = 0; j < 4; j++)
#pragma unroll
        for (int i = 0; i < 4; i++) {
          const int nloc = j * 16 + l16;
          const int m = wm * 64 + i * 16 + quad * 4;
          short4v pk;
#pragma unroll
          for (int r = 0; r < 4; r++) pk[r] = f2bf(acck[i][j][r]);
          *(short4v*)&scratch[nloc * 136 + m] = pk;
        }
    }
    __syncthreads();
    {
      // drain full 64 x 128 tile: 256 threads x 32 shorts
      const int row = tid >> 2;        // 0..63
      const int off = (tid & 3) * 32;  // 0..96
#pragma unroll
      for (int c = 0; c < 4; c++) {
        short8 vv = *(const short8*)&scratch[row * 136 + off + c * 8];
        *(short8*)&kz[(n0 + h * 64 + row) * 512 + m0 + off + c * 8] = vv;
      }
    }
  }
}

// ---------------- vis fp32 (b,c,s) -> visT bf16 (b,s,c) ----------------
__global__ __launch_bounds__(256) void transpose_f2b(
    const float* __restrict__ vis, short* __restrict__ visT) {
  __shared__ alignas(16) short buf[64][68];
  const int tid = threadIdx.x;
  const long bz = blockIdx.z;
  const long s0 = (long)blockIdx.x * 64;
  const long c0 = (long)blockIdx.y * 64;
  const float* src = vis + bz * 512 * 4096;
  short* dst = visT + bz * 4096 * 512;
  const int tr = tid >> 4;
  const int tc4 = (tid & 15) * 4;
#pragma unroll
  for (int i = 0; i < 4; i++) {
    const int c = tr + i * 16;
    float4v val = *(const float4v*)&src[(c0 + c) * 4096 + s0 + tc4];
    buf[tc4 + 0][c] = f2bf(val[0]);
    buf[tc4 + 1][c] = f2bf(val[1]);
    buf[tc4 + 2][c] = f2bf(val[2]);
    buf[tc4 + 3][c] = f2bf(val[3]);
  }
  __syncthreads();
#pragma unroll
  for (int i = 0; i < 4; i++) {
    const int s = tr + i * 16;
    short4v val = *(const short4v*)&buf[s][tc4];
    *(short4v*)&dst[(s0 + s) * 512 + c0 + tc4] = val;
  }
}

// ---------------- attention partial: block = (head, batch, s-chunk) ----------------
// Each block covers 4096/NCH s-positions; no-max softmax partials.
// XOR-swizzled LDS; k/v fragment reads hoisted to registers so next chunk's
// staging overlaps QK -> softmax -> PV. The "lp ready" barrier is a raw
// s_barrier + lgkmcnt(0) only — the next chunk's k/v staging stays in flight
// through PV (a __syncthreads here would emit vmcnt(0) and drain it).
__global__ __launch_bounds__(256) void attn_part(
    const short* __restrict__ q, const short* __restrict__ kws,
    const short* __restrict__ vws, float* __restrict__ Opart,
    float* __restrict__ lpart, int b0) {
  const int h = blockIdx.x;
  const int bz = blockIdx.y;
  const int ch = blockIdx.z;
  const int tid = threadIdx.x;
  const int lane = tid & 63, w = tid >> 6;
  const int quad = lane >> 4, l16 = lane & 15;

  __shared__ alignas(16) short lq[64 * 64];
  __shared__ alignas(16) short lk[128 * 64];
  __shared__ alignas(16) short lv[64 * 128];
  __shared__ alignas(16) short lp[64 * 128];
  __shared__ float lsum[64];

  const short* qb = q + ((long)(b0 + bz) * 64) * 512 + h * 64;
  const short* kb = kws + (long)bz * 4096 * 512 + h * 64;
  const short* vb = vws + (long)bz * 512 * 4096 + (long)h * 64 * 4096;

  if (tid < 64) lsum[tid] = 0.0f;
  {
    // lq: 64 rows x 8 chunks; slot (r, c) <- global chunk c ^ (r&7)
    const int qr = tid >> 3;
    const int qc = ((tid & 7) ^ (qr & 7)) * 8;
    load_lds16(&qb[qr * 512 + qc], &lq[tid * 8]);
    load_lds16(&qb[(32 + qr) * 512 + qc], &lq[2048 + tid * 8]);  // (32+qr)&7 == qr&7
  }
  // prologue: stage first k/v chunk (overlaps q fragment setup)
  const int s0_first = ch * (4096 / NCH);
  const int send = s0_first + (4096 / NCH);
#pragma unroll
  for (int it = 0; it < 4; it++) {
    const int li = tid + it * 256;
    const int kr = li >> 3;
    const int kc = ((li & 7) ^ (kr & 7)) * 8;
    load_lds16(&kb[(long)(s0_first + kr) * 512 + kc], &lk[li * 8]);
  }
#pragma unroll
  for (int it = 0; it < 4; it++) {
    const int li = tid + it * 256;
    const int vr = li >> 4;
    const int vc = ((li & 15) ^ (vr & 7)) * 8;
    load_lds16(&vb[(long)vr * 4096 + s0_first + vc], &lv[li * 8]);
  }
  __syncthreads();  // lq + first k/v landed

  short8 aq[4][2];
#pragma unroll
  for (int mt = 0; mt < 4; mt++)
#pragma unroll
    for (int ks = 0; ks < 2; ks++) {
      const int ra = mt * 16 + l16;
      aq[mt][ks] = *(const short8*)&lq[ra * 64 + (((ks * 4 + quad) ^ (ra & 7)) * 8)];
    }

  float4v osc[4];
#pragma unroll
  for (int mt = 0; mt < 4; mt++) osc[mt] = (float4v)0.0f;
  float lrow[4][4] = {};

  for (int s0 = s0_first; s0 < send; s0 += 128) {
    // pull ALL lk/lv fragments for this chunk into regs
    short8 bk[2][2];  // [ks][jn]
#pragma unroll
    for (int ks = 0; ks < 2; ks++)
#pragma unroll
      for (int jn = 0; jn < 2; jn++) {
        const int rb = (2 * w + jn) * 16 + l16;
        bk[ks][jn] = *(const short8*)&lk[rb * 64 + (((ks * 4 + quad) ^ (rb & 7)) * 8)];
      }
    short8 bv[4];
#pragma unroll
    for (int ks = 0; ks < 4; ks++) {
      const int rv = w * 16 + l16;
      bv[ks] = *(const short8*)&lv[rv * 128 + (((ks * 4 + quad) ^ (rv & 7)) * 8)];
    }
    __syncthreads();  // all waves done with lk/lv (also drains prior staging)

    if (s0 + 128 < send) {  // stage next chunk; overlaps QK+softmax+PV
#pragma unroll
      for (int it = 0; it < 4; it++) {
        const int li = tid + it * 256;
        const int kr = li >> 3;
        const int kc = ((li & 7) ^ (kr & 7)) * 8;
        load_lds16(&kb[(long)(s0 + 128 + kr) * 512 + kc], &lk[li * 8]);
      }
#pragma unroll
      for (int it = 0; it < 4; it++) {
        const int li = tid + it * 256;
        const int vr = li >> 4;
        const int vc = ((li & 15) ^ (vr & 7)) * 8;
        load_lds16(&vb[(long)vr * 4096 + s0 + 128 + vc], &lv[li * 8]);
      }
    }

    // scores: wave w covers s-tiles {2w, 2w+1}
    float4v sc[4][2];
#pragma unroll
    for (int mt = 0; mt < 4; mt++)
#pragma unroll
      for (int jn = 0; jn < 2; jn++) sc[mt][jn] = (float4v)0.0f;
#pragma unroll
    for (int ks = 0; ks < 2; ks++)
#pragma unroll
      for (int mt = 0; mt < 4; mt++)
#pragma unroll
        for (int jn = 0; jn < 2; jn++)
          sc[mt][jn] = mfma16x16x32(aq[mt][ks], bk[ks][jn], sc[mt][jn]);

    // p = exp(clamped score); bf16-quantized row sums; park p in lp (row-XOR).
#pragma unroll
    for (int mt = 0; mt < 4; mt++)
#pragma unroll
      for (int jn = 0; jn < 2; jn++)
#pragma unroll
        for (int r = 0; r < 4; r++) {
          const float scv = fminf(fmaxf(sc[mt][jn][r], -80.0f), 30.0f);
          const short sp = f2bf(__expf(scv));
          lrow[mt][r] += bf2f(sp);
          const int rowp = mt * 16 + quad * 4 + r;
          const int col = (2 * w + jn) * 16 + l16;
          lp[rowp * 128 + (((col >> 3) ^ (rowp & 7)) * 8) + (col & 7)] = sp;
        }
    // lp ready: raw barrier — k/v staging must STAY in flight through PV
    asm volatile("s_waitcnt lgkmcnt(0)" ::: "memory");
    __builtin_amdgcn_sched_barrier(0);
    __builtin_amdgcn_s_barrier();

    // PV from lp (this-iter data) and bv regs
#pragma unroll
    for (int ks = 0; ks < 4; ks++)
#pragma unroll
      for (int mt = 0; mt < 4; mt++) {
        const int rp = mt * 16 + l16;
        const short8 ap = *(const short8*)&lp[rp * 128 + (((ks * 4 + quad) ^ (rp & 7)) * 8)];
        osc[mt] = mfma16x16x32(ap, bv[ks], osc[mt]);
      }
    __syncthreads();  // everyone done with lp; staging drains before next frag reads
  }

#pragma unroll
  for (int mt = 0; mt < 4; mt++)
#pragma unroll
    for (int r = 0; r < 4; r++) {
      float v = lrow[mt][r];
      v += __shfl_xor(v, 1);
      v += __shfl_xor(v, 2);
      v += __shfl_xor(v, 4);
      v += __shfl_xor(v, 8);
      if (l16 == 0) atomicAdd(&lsum[mt * 16 + quad * 4 + r], v);
    }
  __syncthreads();

  const long bh = bz * 8 + h;
  float* op = Opart + ((bh * NCH + ch) * 64) * 64 + w * 16 + l16;
#pragma unroll
  for (int mt = 0; mt < 4; mt++)
#pragma unroll
    for (int r = 0; r < 4; r++)
      op[(long)(mt * 16 + quad * 4 + r) * 64] = osc[mt][r];
  if (tid < 64) lpart[(bh * NCH + ch) * 64 + tid] = lsum[tid];
}

// ---------------- combine attention partials -> tmp bf16 (b,t,i) ----------------
__global__ __launch_bounds__(256) void attn_combine(
    const float* __restrict__ Opart, const float* __restrict__ lpart,
    short* __restrict__ tmp, int b0, int nbh) {
  const int total = nbh * 4096;
  for (int idx = blockIdx.x * 256 + threadIdx.x; idx < total;
       idx += gridDim.x * 256) {
    const int bh = idx >> 12;
    const int td = idx & 4095;
    const int t = td >> 6, d = td & 63;
    float o = 0.0f, l = 0.0f;
#pragma unroll
    for (int c = 0; c < NCH; c++) {
      o += Opart[((long)bh * NCH + c) * 4096 + td];
      l += lpart[(bh * NCH + c) * 64 + t];
    }
    const int b = b0 + (bh >> 3), h = bh & 7;
    tmp[((long)b * 64 + t) * 512 + h * 64 + d] = f2bf(o / l);
  }
}

// ---------------- launch ----------------
extern "C" void kernel_launch(void* const* d_in, const int* in_sizes, int n_in,
                              void* d_out, int out_size, void* d_ws, size_t ws_size,
                              hipStream_t stream) {
  (void)in_sizes; (void)n_in; (void)out_size;
  const float* vis = (const float*)d_in[0];   // [16][512][4096] fp32
  const float* lang = (const float*)d_in[1];  // [16][64][512]  fp32
  const float* Wq = (const float*)d_in[3];    // [512][512] fp32
  const float* Wk = (const float*)d_in[4];
  const float* Wv = (const float*)d_in[5];
  const float* Wo = (const float*)d_in[6];
  float* out = (float*)d_out;                 // [16][64][512] fp32

  char* ws = (char*)d_ws;
  const size_t MB = 1 << 20;
  short* q_ws = (short*)(ws + 0 * MB);
  short* tmp_ws = (short*)(ws + 1 * MB);
  short* langb = (short*)(ws + 2 * MB);
  short* Wqb = (short*)(ws + 3 * MB);
  short* Wkb = (short*)(ws + 3 * MB + 512 * 1024);
  short* Wvb = (short*)(ws + 4 * MB);
  short* Wob = (short*)(ws + 4 * MB + 512 * 1024);
  char* grp = ws + 5 * MB;

  const long batch_elems = 4096l * 512;
  int g = 16;
  const int cands[5] = {1, 2, 4, 8, 16};
  for (int ci = 0; ci < 5; ci++) {
    const size_t need = 5 * MB + 3ull * (16 / cands[ci]) * batch_elems * 2;
    if (need <= ws_size) { g = cands[ci]; break; }
  }
  const int Bg = 16 / g;
  short* visT = (short*)grp;                    // [Bg][4096][512]
  short* k_ws = visT + (long)Bg * batch_elems;  // [Bg][4096][512] (s,i)
  short* v_ws = k_ws + (long)Bg * batch_elems;  // [Bg][512][4096] (i,s)
  // attn partials alias visT (dead by attn time)
  float* Opart = (float*)visT;
  float* lptr = Opart + (long)Bg * 8 * NCH * 4096;

  convert5<<<dim3(128, 5), 256, 0, stream>>>(lang, langb, Wq, Wqb, Wk, Wkb,
                                             Wv, Wvb, Wo, Wob);

  // q = SCALE * lang @ Wq^T
  gemm_nt<0><<<dim3(4, 8), 256, 0, stream>>>(langb, Wqb, q_ws, 512, 512, 0.125f);

  for (int gi = 0; gi < g; gi++) {
    const int b0 = gi * Bg;
    transpose_f2b<<<dim3(64, 8, Bg), 256, 0, stream>>>(vis + (long)b0 * batch_elems, visT);
    gemm_kv<<<dim3(32, 4, Bg), 256, 0, stream>>>(Wkb, Wvb, visT, batch_elems,
                                                 k_ws, v_ws, batch_elems);
    attn_part<<<dim3(8, Bg, NCH), 256, 0, stream>>>(q_ws, k_ws, v_ws, Opart, lptr, b0);
    attn_combine<<<512, 256, 0, stream>>>(Opart, lptr, tmp_ws, b0, Bg * 8);
  }

  // out = tmp @ Wo^T, fp32 epilogue
  gemm_nt<1><<<dim3(4, 8), 256, 0, stream>>>(tmp_ws, Wob, out, 512, 512, 1.0f);
}

// Round 4
// 336.725 us; speedup vs baseline: 1.1271x; 1.0121x over previous
//
#include <hip/hip_runtime.h>
#include <stdint.h>

// ---------------- common helpers ----------------
typedef __attribute__((ext_vector_type(8))) short short8;
typedef __attribute__((ext_vector_type(4))) short short4v;
typedef __attribute__((ext_vector_type(4))) float float4v;
typedef __attribute__((ext_vector_type(8))) __bf16 bf16x8;

#define NCH 4  // attention S-dim split factor

__device__ __forceinline__ float4v mfma16x16x32(short8 a, short8 b, float4v c) {
  return __builtin_amdgcn_mfma_f32_16x16x32_bf16(
      __builtin_bit_cast(bf16x8, a), __builtin_bit_cast(bf16x8, b), c, 0, 0, 0);
}

// float -> bf16 (RNE), as raw short
__device__ __forceinline__ short f2bf(float f) {
  uint32_t u = __builtin_bit_cast(uint32_t, f);
  u += 0x7fffu + ((u >> 16) & 1u);
  return (short)(u >> 16);
}

__device__ __forceinline__ float bf2f(short s) {
  return __builtin_bit_cast(float, ((uint32_t)(uint16_t)s) << 16);
}

// async 16B global->LDS. LDS dst = wave-uniform base + lane*16 at all sites.
__device__ __forceinline__ void load_lds16(const short* g, short* l) {
  __builtin_amdgcn_global_load_lds(
      (const __attribute__((address_space(1))) void*)g,
      (__attribute__((address_space(3))) void*)l, 16, 0, 0);
}

// ---------------- fused fp32 -> bf16 for lang + 4 weights ----------------
__global__ __launch_bounds__(256) void convert5(
    const float* __restrict__ sl, short* __restrict__ dl,
    const float* __restrict__ s1, short* __restrict__ d1,
    const float* __restrict__ s2, short* __restrict__ d2,
    const float* __restrict__ s3, short* __restrict__ d3,
    const float* __restrict__ s4, short* __restrict__ d4) {
  const float* src; short* dst; int n4;
  switch (blockIdx.y) {
    case 0: src = sl; dst = dl; n4 = 131072; break;
    case 1: src = s1; dst = d1; n4 = 65536; break;
    case 2: src = s2; dst = d2; n4 = 65536; break;
    case 3: src = s3; dst = d3; n4 = 65536; break;
    default: src = s4; dst = d4; n4 = 65536; break;
  }
  const int stride = gridDim.x * blockDim.x;
  for (int i = blockIdx.x * blockDim.x + threadIdx.x; i < n4; i += stride) {
    float4v v = *(const float4v*)(src + (long)i * 4);
    short4v o;
#pragma unroll
    for (int r = 0; r < 4; r++) o[r] = f2bf(v[r]);
    *(short4v*)(dst + (long)i * 4) = o;
  }
}

// ---------------- small NT GEMM (q / out projections) ----------------
// C[m,n] = scale * sum_k A[m,k]*B[n,k]; 128x128 tile, BK=32, 4 waves.
// v4: TRIPLE-buffered LDS, ONE barrier + one counted vmcnt per K-step, no
// explicit lgkm drain — stage(it+2) targets the buffer whose readers all
// finished before barrier(it), so the old read-done barrier is unnecessary
// and the compiler interleaves ds_reads into the MFMA cluster freely.
template <int OUT_F32>
__global__ __launch_bounds__(256) void gemm_nt(
    const short* __restrict__ A, const short* __restrict__ B,
    void* __restrict__ C, int K, int ldc, float scale) {
  __shared__ alignas(16) short smem[24576];  // 3 x (lA 4096 | lB 4096) shorts
  const int tid = threadIdx.x;
  const int lane = tid & 63, w = tid >> 6;
  const int quad = lane >> 4, l16 = lane & 15;
  const int wm = w >> 1, wn = w & 1;
  const long m0 = (long)blockIdx.y * 128, n0 = (long)blockIdx.x * 128;

  float4v acc[4][4];
#pragma unroll
  for (int i = 0; i < 4; i++)
#pragma unroll
    for (int j = 0; j < 4; j++) acc[i][j] = (float4v)0.0f;

  const int srow = tid >> 2;  // 0..63 (also used at +64)
  const int scol = (((tid & 3) ^ ((srow >> 1) & 3))) * 8;  // swizzled source chunk
  const int nit = K >> 5;

#define STAGE_NT(t, base)                                                       \
  do {                                                                          \
    load_lds16(&A[(m0 + srow) * K + (t) * 32 + scol], &smem[(base) + tid * 8]); \
    load_lds16(&A[(m0 + 64 + srow) * K + (t) * 32 + scol],                      \
               &smem[(base) + 2048 + tid * 8]);                                 \
    load_lds16(&B[(n0 + srow) * K + (t) * 32 + scol],                           \
               &smem[(base) + 4096 + tid * 8]);                                 \
    load_lds16(&B[(n0 + 64 + srow) * K + (t) * 32 + scol],                      \
               &smem[(base) + 6144 + tid * 8]);                                 \
  } while (0)

  // prologue: stage tiles 0 and 1
  STAGE_NT(0, 0);
  if (nit > 1) STAGE_NT(1, 8192);

  for (int it = 0; it < nit; ++it) {
    const int base = (it % 3) * 8192;
    // tile it landed when <= 4 of my loads remain outstanding (tile it+1's)
    if (it + 1 < nit) asm volatile("s_waitcnt vmcnt(4)" ::: "memory");
    else              asm volatile("s_waitcnt vmcnt(0)" ::: "memory");
    __builtin_amdgcn_s_barrier();  // tile it fully landed for ALL waves

    // stage tile it+2 into the buffer whose readers finished pre-barrier(it)
    if (it + 2 < nit) STAGE_NT(it + 2, ((it + 2) % 3) * 8192);

    const short* lA = &smem[base];
    const short* lB = &smem[base + 4096];
    short8 af[4], bf[4];
#pragma unroll
    for (int t = 0; t < 4; t++) {
      const int ra = wm * 64 + t * 16 + l16;
      const int rb = wn * 64 + t * 16 + l16;
      af[t] = *(const short8*)&lA[ra * 32 + ((quad ^ ((ra >> 1) & 3)) * 8)];
      bf[t] = *(const short8*)&lB[rb * 32 + ((quad ^ ((rb >> 1) & 3)) * 8)];
    }
    __builtin_amdgcn_s_setprio(1);
#pragma unroll
    for (int i = 0; i < 4; i++)
#pragma unroll
      for (int j = 0; j < 4; j++)
        acc[i][j] = mfma16x16x32(af[i], bf[j], acc[i][j]);
    __builtin_amdgcn_s_setprio(0);
  }
#undef STAGE_NT

  const int cm = wm * 64 + quad * 4;
  const int cn = wn * 64 + l16;
  if (OUT_F32) {
    float* Cf = (float*)C;
#pragma unroll
    for (int i = 0; i < 4; i++)
#pragma unroll
      for (int j = 0; j < 4; j++) {
        const long gn = n0 + cn + j * 16;
#pragma unroll
        for (int r = 0; r < 4; r++)
          Cf[(m0 + cm + i * 16 + r) * (long)ldc + gn] = acc[i][j][r] * scale;
      }
  } else {
    short* Cs = (short*)C;
#pragma unroll
    for (int i = 0; i < 4; i++)
#pragma unroll
      for (int j = 0; j < 4; j++) {
        const long gn = n0 + cn + j * 16;
#pragma unroll
        for (int r = 0; r < 4; r++)
          Cs[(m0 + cm + i * 16 + r) * (long)ldc + gn] = f2bf(acc[i][j][r] * scale);
      }
  }
}

// ---------------- fused KV projection ----------------
// v4: 8 waves role-split (w0..3 -> k, w4..7 -> v), TRIPLE-buffered LDS
// (3 x 24 KB = 72 KB), ONE barrier + one counted vmcnt(3) per K-step, no
// explicit lgkm drain and no read-done barrier: with 3 buffers, stage(it+2)
// writes the buffer whose tile-(it-1) readers all finished before
// barrier(it). Compiler schedules ds_read->MFMA with its own counted
// lgkmcnt; setprio(1) wraps the MFMA cluster (waves de-phase across the
// single barrier -> scheduler has role diversity to arbitrate).
// grid=(S/128, I/128, Bg), 512 threads.
__global__ __launch_bounds__(512, 4) void gemm_kv(
    const short* __restrict__ Wk, const short* __restrict__ Wv,
    const short* __restrict__ visT, long sV,
    short* __restrict__ kout, short* __restrict__ vout, long sKV) {
  // 3 buffers x (lWk 4096 | lWv 4096 | lVis 4096) shorts = 72 KB.
  // epilogue scratch (8704 shorts) aliases buffer 0 (dead by then).
  __shared__ alignas(16) short smem[36864];
  const int tid = threadIdx.x;
  const int lane = tid & 63, w = tid >> 6;
  const int quad = lane >> 4, l16 = lane & 15;
  const int role = w >> 2;          // 0 = k, 1 = v
  const int wq = w & 3, wm = wq >> 1, wn = wq & 1;
  const long n0 = (long)blockIdx.x * 128;  // s
  const long m0 = (long)blockIdx.y * 128;  // i
  const short* vis = visT + blockIdx.z * sV;
  short* kz = kout + blockIdx.z * sKV;
  short* vz = vout + blockIdx.z * sKV;

  float4v acc[4][4];
#pragma unroll
  for (int i = 0; i < 4; i++)
#pragma unroll
    for (int j = 0; j < 4; j++) acc[i][j] = (float4v)0.0f;

  const int srow = tid >> 2;  // 0..127
  const int scol = (((tid & 3) ^ ((srow >> 1) & 3))) * 8;  // swizzled source chunk

  const short* gWk = &Wk[(m0 + srow) * 512 + scol];
  const short* gWv = &Wv[(m0 + srow) * 512 + scol];
  const short* gV = &vis[(n0 + srow) * 512 + scol];

#define STAGE_KV(t, base)                                      \
  do {                                                         \
    load_lds16(gWk + (t) * 32, &smem[(base) + tid * 8]);       \
    load_lds16(gWv + (t) * 32, &smem[(base) + 4096 + tid * 8]);\
    load_lds16(gV + (t) * 32, &smem[(base) + 8192 + tid * 8]); \
  } while (0)

  // prologue: stage tiles 0 and 1 (tile 2 staged inside iter 0)
  STAGE_KV(0, 0);
  STAGE_KV(1, 12288);

  for (int it = 0; it < 16; ++it) {
    const int base = (it % 3) * 12288;
    // tile it landed when <= 3 outstanding (tile it+1's own loads)
    if (it < 15) asm volatile("s_waitcnt vmcnt(3)" ::: "memory");
    else         asm volatile("s_waitcnt vmcnt(0)" ::: "memory");
    __builtin_amdgcn_s_barrier();  // tile it fully landed for ALL waves

    // stage tile it+2 -> buffer whose readers finished pre-barrier(it)
    if (it + 2 < 16) STAGE_KV(it + 2, ((it + 2) % 3) * 12288);

    const short* lW = &smem[base + (role ? 4096 : 0)];
    const short* lVis = &smem[base + 8192];
    short8 af[4], bf[4];
#pragma unroll
    for (int t = 0; t < 4; t++) {
      const int ra = wm * 64 + t * 16 + l16;
      const int rb = wn * 64 + t * 16 + l16;
      af[t] = *(const short8*)&lW[ra * 32 + ((quad ^ ((ra >> 1) & 3)) * 8)];
      bf[t] = *(const short8*)&lVis[rb * 32 + ((quad ^ ((rb >> 1) & 3)) * 8)];
    }
    __builtin_amdgcn_s_setprio(1);
#pragma unroll
    for (int i = 0; i < 4; i++)
#pragma unroll
      for (int j = 0; j < 4; j++)
        acc[i][j] = mfma16x16x32(af[i], bf[j], acc[i][j]);
    __builtin_amdgcn_s_setprio(0);
  }
#undef STAGE_KV

  // C/D layout: col(n=s) = lane&15, row(m=i) = quad*4 + reg
  const int cm = wm * 64 + quad * 4;
  const int cn = wn * 64 + l16;

  // v: direct store (i,s)
  if (role == 1) {
#pragma unroll
    for (int i = 0; i < 4; i++)
#pragma unroll
      for (int j = 0; j < 4; j++) {
        const long gn = n0 + cn + j * 16;
#pragma unroll
        for (int r = 0; r < 4; r++)
          vz[(m0 + cm + i * 16 + r) * 4096 + gn] = f2bf(acc[i][j][r]);
      }
  }

  // k: retile through LDS -> coalesced 256B stores of k[s][i]
  short* scratch = smem;  // 64 rows x 136 shorts = 8704 <= 36864
#pragma unroll
  for (int h = 0; h < 2; h++) {
    __syncthreads();
    if (role == 0 && wn == h) {
#pragma unroll
      for (int j = 0; j < 4; j++)
#pragma unroll
        for (int i = 0; i < 4; i++) {
          const int nloc = j * 16 + l16;
          const int m = wm * 64 + i * 16 + quad * 4;
          short4v pk;
#pragma unroll
          for (int r = 0; r < 4; r++) pk[r] = f2bf(acc[i][j][r]);
          *(short4v*)&scratch[nloc * 136 + m] = pk;
        }
    }
    __syncthreads();
    {
      // drain full 64 x 128 tile: 512 threads x 16 shorts
      const int row = tid >> 3;        // 0..63
      const int off = (tid & 7) * 16;  // 0..112
      short8 v0 = *(const short8*)&scratch[row * 136 + off];
      short8 v1 = *(const short8*)&scratch[row * 136 + off + 8];
      *(short8*)&kz[(n0 + h * 64 + row) * 512 + m0 + off] = v0;
      *(short8*)&kz[(n0 + h * 64 + row) * 512 + m0 + off + 8] = v1;
    }
  }
}

// ---------------- vis fp32 (b,c,s) -> visT bf16 (b,s,c) ----------------
__global__ __launch_bounds__(256) void transpose_f2b(
    const float* __restrict__ vis, short* __restrict__ visT) {
  __shared__ alignas(16) short buf[64][68];
  const int tid = threadIdx.x;
  const long bz = blockIdx.z;
  const long s0 = (long)blockIdx.x * 64;
  const long c0 = (long)blockIdx.y * 64;
  const float* src = vis + bz * 512 * 4096;
  short* dst = visT + bz * 4096 * 512;
  const int tr = tid >> 4;
  const int tc4 = (tid & 15) * 4;
#pragma unroll
  for (int i = 0; i < 4; i++) {
    const int c = tr + i * 16;
    float4v val = *(const float4v*)&src[(c0 + c) * 4096 + s0 + tc4];
    buf[tc4 + 0][c] = f2bf(val[0]);
    buf[tc4 + 1][c] = f2bf(val[1]);
    buf[tc4 + 2][c] = f2bf(val[2]);
    buf[tc4 + 3][c] = f2bf(val[3]);
  }
  __syncthreads();
#pragma unroll
  for (int i = 0; i < 4; i++) {
    const int s = tr + i * 16;
    short4v val = *(const short4v*)&buf[s][tc4];
    *(short4v*)&dst[(s0 + s) * 512 + c0 + tc4] = val;
  }
}

// ---------------- attention partial: block = (head, batch, s-chunk) ----------------
// Each block covers 4096/NCH s-positions; no-max softmax partials.
// XOR-swizzled LDS; k/v fragment reads hoisted to registers so next chunk's
// staging overlaps QK -> softmax -> PV. The "lp ready" barrier is a raw
// s_barrier + lgkmcnt(0) only — the next chunk's k/v staging stays in flight
// through PV (a __syncthreads here would emit vmcnt(0) and drain it).
__global__ __launch_bounds__(256) void attn_part(
    const short* __restrict__ q, const short* __restrict__ kws,
    const short* __restrict__ vws, float* __restrict__ Opart,
    float* __restrict__ lpart, int b0) {
  const int h = blockIdx.x;
  const int bz = blockIdx.y;
  const int ch = blockIdx.z;
  const int tid = threadIdx.x;
  const int lane = tid & 63, w = tid >> 6;
  const int quad = lane >> 4, l16 = lane & 15;

  __shared__ alignas(16) short lq[64 * 64];
  __shared__ alignas(16) short lk[128 * 64];
  __shared__ alignas(16) short lv[64 * 128];
  __shared__ alignas(16) short lp[64 * 128];
  __shared__ float lsum[64];

  const short* qb = q + ((long)(b0 + bz) * 64) * 512 + h * 64;
  const short* kb = kws + (long)bz * 4096 * 512 + h * 64;
  const short* vb = vws + (long)bz * 512 * 4096 + (long)h * 64 * 4096;

  if (tid < 64) lsum[tid] = 0.0f;
  {
    // lq: 64 rows x 8 chunks; slot (r, c) <- global chunk c ^ (r&7)
    const int qr = tid >> 3;
    const int qc = ((tid & 7) ^ (qr & 7)) * 8;
    load_lds16(&qb[qr * 512 + qc], &lq[tid * 8]);
    load_lds16(&qb[(32 + qr) * 512 + qc], &lq[2048 + tid * 8]);  // (32+qr)&7 == qr&7
  }
  // prologue: stage first k/v chunk (overlaps q fragment setup)
  const int s0_first = ch * (4096 / NCH);
  const int send = s0_first + (4096 / NCH);
#pragma unroll
  for (int it = 0; it < 4; it++) {
    const int li = tid + it * 256;
    const int kr = li >> 3;
    const int kc = ((li & 7) ^ (kr & 7)) * 8;
    load_lds16(&kb[(long)(s0_first + kr) * 512 + kc], &lk[li * 8]);
  }
#pragma unroll
  for (int it = 0; it < 4; it++) {
    const int li = tid + it * 256;
    const int vr = li >> 4;
    const int vc = ((li & 15) ^ (vr & 7)) * 8;
    load_lds16(&vb[(long)vr * 4096 + s0_first + vc], &lv[li * 8]);
  }
  __syncthreads();  // lq + first k/v landed

  short8 aq[4][2];
#pragma unroll
  for (int mt = 0; mt < 4; mt++)
#pragma unroll
    for (int ks = 0; ks < 2; ks++) {
      const int ra = mt * 16 + l16;
      aq[mt][ks] = *(const short8*)&lq[ra * 64 + (((ks * 4 + quad) ^ (ra & 7)) * 8)];
    }

  float4v osc[4];
#pragma unroll
  for (int mt = 0; mt < 4; mt++) osc[mt] = (float4v)0.0f;
  float lrow[4][4] = {};

  for (int s0 = s0_first; s0 < send; s0 += 128) {
    // pull ALL lk/lv fragments for this chunk into regs
    short8 bk[2][2];  // [ks][jn]
#pragma unroll
    for (int ks = 0; ks < 2; ks++)
#pragma unroll
      for (int jn = 0; jn < 2; jn++) {
        const int rb = (2 * w + jn) * 16 + l16;
        bk[ks][jn] = *(const short8*)&lk[rb * 64 + (((ks * 4 + quad) ^ (rb & 7)) * 8)];
      }
    short8 bv[4];
#pragma unroll
    for (int ks = 0; ks < 4; ks++) {
      const int rv = w * 16 + l16;
      bv[ks] = *(const short8*)&lv[rv * 128 + (((ks * 4 + quad) ^ (rv & 7)) * 8)];
    }
    __syncthreads();  // all waves done with lk/lv (also drains prior staging)

    if (s0 + 128 < send) {  // stage next chunk; overlaps QK+softmax+PV
#pragma unroll
      for (int it = 0; it < 4; it++) {
        const int li = tid + it * 256;
        const int kr = li >> 3;
        const int kc = ((li & 7) ^ (kr & 7)) * 8;
        load_lds16(&kb[(long)(s0 + 128 + kr) * 512 + kc], &lk[li * 8]);
      }
#pragma unroll
      for (int it = 0; it < 4; it++) {
        const int li = tid + it * 256;
        const int vr = li >> 4;
        const int vc = ((li & 15) ^ (vr & 7)) * 8;
        load_lds16(&vb[(long)vr * 4096 + s0 + 128 + vc], &lv[li * 8]);
      }
    }

    // scores: wave w covers s-tiles {2w, 2w+1}
    float4v sc[4][2];
#pragma unroll
    for (int mt = 0; mt < 4; mt++)
#pragma unroll
      for (int jn = 0; jn < 2; jn++) sc[mt][jn] = (float4v)0.0f;
#pragma unroll
    for (int ks = 0; ks < 2; ks++)
#pragma unroll
      for (int mt = 0; mt < 4; mt++)
#pragma unroll
        for (int jn = 0; jn < 2; jn++)
          sc[mt][jn] = mfma16x16x32(aq[mt][ks], bk[ks][jn], sc[mt][jn]);

    // p = exp(clamped score); bf16-quantized row sums; park p in lp (row-XOR).
#pragma unroll
    for (int mt = 0; mt < 4; mt++)
#pragma unroll
      for (int jn = 0; jn < 2; jn++)
#pragma unroll
        for (int r = 0; r < 4; r++) {
          const float scv = fminf(fmaxf(sc[mt][jn][r], -80.0f), 30.0f);
          const short sp = f2bf(__expf(scv));
          lrow[mt][r] += bf2f(sp);
          const int rowp = mt * 16 + quad * 4 + r;
          const int col = (2 * w + jn) * 16 + l16;
          lp[rowp * 128 + (((col >> 3) ^ (rowp & 7)) * 8) + (col & 7)] = sp;
        }
    // lp ready: raw barrier — k/v staging must STAY in flight through PV
    asm volatile("s_waitcnt lgkmcnt(0)" ::: "memory");
    __builtin_amdgcn_sched_barrier(0);
    __builtin_amdgcn_s_barrier();

    // PV from lp (this-iter data) and bv regs
#pragma unroll
    for (int ks = 0; ks < 4; ks++)
#pragma unroll
      for (int mt = 0; mt < 4; mt++) {
        const int rp = mt * 16 + l16;
        const short8 ap = *(const short8*)&lp[rp * 128 + (((ks * 4 + quad) ^ (rp & 7)) * 8)];
        osc[mt] = mfma16x16x32(ap, bv[ks], osc[mt]);
      }
    __syncthreads();  // everyone done with lp; staging drains before next frag reads
  }

#pragma unroll
  for (int mt = 0; mt < 4; mt++)
#pragma unroll
    for (int r = 0; r < 4; r++) {
      float v = lrow[mt][r];
      v += __shfl_xor(v, 1);
      v += __shfl_xor(v, 2);
      v += __shfl_xor(v, 4);
      v += __shfl_xor(v, 8);
      if (l16 == 0) atomicAdd(&lsum[mt * 16 + quad * 4 + r], v);
    }
  __syncthreads();

  const long bh = bz * 8 + h;
  float* op = Opart + ((bh * NCH + ch) * 64) * 64 + w * 16 + l16;
#pragma unroll
  for (int mt = 0; mt < 4; mt++)
#pragma unroll
    for (int r = 0; r < 4; r++)
      op[(long)(mt * 16 + quad * 4 + r) * 64] = osc[mt][r];
  if (tid < 64) lpart[(bh * NCH + ch) * 64 + tid] = lsum[tid];
}

// ---------------- combine attention partials -> tmp bf16 (b,t,i) ----------------
__global__ __launch_bounds__(256) void attn_combine(
    const float* __restrict__ Opart, const float* __restrict__ lpart,
    short* __restrict__ tmp, int b0, int nbh) {
  const int total = nbh * 4096;
  for (int idx = blockIdx.x * 256 + threadIdx.x; idx < total;
       idx += gridDim.x * 256) {
    const int bh = idx >> 12;
    const int td = idx & 4095;
    const int t = td >> 6, d = td & 63;
    float o = 0.0f, l = 0.0f;
#pragma unroll
    for (int c = 0; c < NCH; c++) {
      o += Opart[((long)bh * NCH + c) * 4096 + td];
      l += lpart[(bh * NCH + c) * 64 + t];
    }
    const int b = b0 + (bh >> 3), h = bh & 7;
    tmp[((long)b * 64 + t) * 512 + h * 64 + d] = f2bf(o / l);
  }
}

// ---------------- launch ----------------
extern "C" void kernel_launch(void* const* d_in, const int* in_sizes, int n_in,
                              void* d_out, int out_size, void* d_ws, size_t ws_size,
                              hipStream_t stream) {
  (void)in_sizes; (void)n_in; (void)out_size;
  const float* vis = (const float*)d_in[0];   // [16][512][4096] fp32
  const float* lang = (const float*)d_in[1];  // [16][64][512]  fp32
  const float* Wq = (const float*)d_in[3];    // [512][512] fp32
  const float* Wk = (const float*)d_in[4];
  const float* Wv = (const float*)d_in[5];
  const float* Wo = (const float*)d_in[6];
  float* out = (float*)d_out;                 // [16][64][512] fp32

  char* ws = (char*)d_ws;
  const size_t MB = 1 << 20;
  short* q_ws = (short*)(ws + 0 * MB);
  short* tmp_ws = (short*)(ws + 1 * MB);
  short* langb = (short*)(ws + 2 * MB);
  short* Wqb = (short*)(ws + 3 * MB);
  short* Wkb = (short*)(ws + 3 * MB + 512 * 1024);
  short* Wvb = (short*)(ws + 4 * MB);
  short* Wob = (short*)(ws + 4 * MB + 512 * 1024);
  char* grp = ws + 5 * MB;

  const long batch_elems = 4096l * 512;
  int g = 16;
  const int cands[5] = {1, 2, 4, 8, 16};
  for (int ci = 0; ci < 5; ci++) {
    const size_t need = 5 * MB + 3ull * (16 / cands[ci]) * batch_elems * 2;
    if (need <= ws_size) { g = cands[ci]; break; }
  }
  const int Bg = 16 / g;
  short* visT = (short*)grp;                    // [Bg][4096][512]
  short* k_ws = visT + (long)Bg * batch_elems;  // [Bg][4096][512] (s,i)
  short* v_ws = k_ws + (long)Bg * batch_elems;  // [Bg][512][4096] (i,s)
  // attn partials alias visT (dead by attn time)
  float* Opart = (float*)visT;
  float* lptr = Opart + (long)Bg * 8 * NCH * 4096;

  convert5<<<dim3(128, 5), 256, 0, stream>>>(lang, langb, Wq, Wqb, Wk, Wkb,
                                             Wv, Wvb, Wo, Wob);

  // q = SCALE * lang @ Wq^T
  gemm_nt<0><<<dim3(4, 8), 256, 0, stream>>>(langb, Wqb, q_ws, 512, 512, 0.125f);

  for (int gi = 0; gi < g; gi++) {
    const int b0 = gi * Bg;
    transpose_f2b<<<dim3(64, 8, Bg), 256, 0, stream>>>(vis + (long)b0 * batch_elems, visT);
    gemm_kv<<<dim3(32, 4, Bg), 512, 0, stream>>>(Wkb, Wvb, visT, batch_elems,
                                                 k_ws, v_ws, batch_elems);
    attn_part<<<dim3(8, Bg, NCH), 256, 0, stream>>>(q_ws, k_ws, v_ws, Opart, lptr, b0);
    attn_combine<<<512, 256, 0, stream>>>(Opart, lptr, tmp_ws, b0, Bg * 8);
  }

  // out = tmp @ Wo^T, fp32 epilogue
  gemm_nt<1><<<dim3(4, 8), 256, 0, stream>>>(tmp_ws, Wob, out, 512, 512, 1.0f);
}

// Round 5
// 331.467 us; speedup vs baseline: 1.1449x; 1.0159x over previous
//
#include <hip/hip_runtime.h>
#include <stdint.h>

// ---------------- common helpers ----------------
typedef __attribute__((ext_vector_type(8))) short short8;
typedef __attribute__((ext_vector_type(4))) short short4v;
typedef __attribute__((ext_vector_type(4))) float float4v;
typedef __attribute__((ext_vector_type(2))) unsigned int uint2v;
typedef __attribute__((ext_vector_type(8))) __bf16 bf16x8;

#define NCH 4  // attention S-dim split factor

__device__ __forceinline__ float4v mfma16x16x32(short8 a, short8 b, float4v c) {
  return __builtin_amdgcn_mfma_f32_16x16x32_bf16(
      __builtin_bit_cast(bf16x8, a), __builtin_bit_cast(bf16x8, b), c, 0, 0, 0);
}

// float -> bf16 (RNE), as raw short
__device__ __forceinline__ short f2bf(float f) {
  uint32_t u = __builtin_bit_cast(uint32_t, f);
  u += 0x7fffu + ((u >> 16) & 1u);
  return (short)(u >> 16);
}

__device__ __forceinline__ float bf2f(short s) {
  return __builtin_bit_cast(float, ((uint32_t)(uint16_t)s) << 16);
}

// pack two f32 -> two bf16 (RNE) in one u32 (lo = a, hi = b)
__device__ __forceinline__ uint32_t cvt_pk_bf16(float a, float b) {
  uint32_t r;
  asm("v_cvt_pk_bf16_f32 %0, %1, %2" : "=v"(r) : "v"(a), "v"(b));
  return r;
}

// async 16B global->LDS. LDS dst = wave-uniform base + lane*16 at all sites.
__device__ __forceinline__ void load_lds16(const short* g, short* l) {
  __builtin_amdgcn_global_load_lds(
      (const __attribute__((address_space(1))) void*)g,
      (__attribute__((address_space(3))) void*)l, 16, 0, 0);
}

// ---------------- fused fp32 -> bf16 for lang + 4 weights ----------------
__global__ __launch_bounds__(256) void convert5(
    const float* __restrict__ sl, short* __restrict__ dl,
    const float* __restrict__ s1, short* __restrict__ d1,
    const float* __restrict__ s2, short* __restrict__ d2,
    const float* __restrict__ s3, short* __restrict__ d3,
    const float* __restrict__ s4, short* __restrict__ d4) {
  const float* src; short* dst; int n4;
  switch (blockIdx.y) {
    case 0: src = sl; dst = dl; n4 = 131072; break;
    case 1: src = s1; dst = d1; n4 = 65536; break;
    case 2: src = s2; dst = d2; n4 = 65536; break;
    case 3: src = s3; dst = d3; n4 = 65536; break;
    default: src = s4; dst = d4; n4 = 65536; break;
  }
  const int stride = gridDim.x * blockDim.x;
  for (int i = blockIdx.x * blockDim.x + threadIdx.x; i < n4; i += stride) {
    float4v v = *(const float4v*)(src + (long)i * 4);
    short4v o;
#pragma unroll
    for (int r = 0; r < 4; r++) o[r] = f2bf(v[r]);
    *(short4v*)(dst + (long)i * 4) = o;
  }
}

// ---------------- small NT GEMM (q / out projections) ----------------
// C[m,n] = scale * sum_k A[m,k]*B[n,k]; 128x128 tile, BK=32, 4 waves.
// TRIPLE-buffered LDS, ONE barrier + one counted vmcnt per K-step.
template <int OUT_F32>
__global__ __launch_bounds__(256) void gemm_nt(
    const short* __restrict__ A, const short* __restrict__ B,
    void* __restrict__ C, int K, int ldc, float scale) {
  __shared__ alignas(16) short smem[24576];  // 3 x (lA 4096 | lB 4096) shorts
  const int tid = threadIdx.x;
  const int lane = tid & 63, w = tid >> 6;
  const int quad = lane >> 4, l16 = lane & 15;
  const int wm = w >> 1, wn = w & 1;
  const long m0 = (long)blockIdx.y * 128, n0 = (long)blockIdx.x * 128;

  float4v acc[4][4];
#pragma unroll
  for (int i = 0; i < 4; i++)
#pragma unroll
    for (int j = 0; j < 4; j++) acc[i][j] = (float4v)0.0f;

  const int srow = tid >> 2;  // 0..63 (also used at +64)
  const int scol = (((tid & 3) ^ ((srow >> 1) & 3))) * 8;  // swizzled source chunk
  const int nit = K >> 5;

#define STAGE_NT(t, base)                                                       \
  do {                                                                          \
    load_lds16(&A[(m0 + srow) * K + (t) * 32 + scol], &smem[(base) + tid * 8]); \
    load_lds16(&A[(m0 + 64 + srow) * K + (t) * 32 + scol],                      \
               &smem[(base) + 2048 + tid * 8]);                                 \
    load_lds16(&B[(n0 + srow) * K + (t) * 32 + scol],                           \
               &smem[(base) + 4096 + tid * 8]);                                 \
    load_lds16(&B[(n0 + 64 + srow) * K + (t) * 32 + scol],                      \
               &smem[(base) + 6144 + tid * 8]);                                 \
  } while (0)

  // prologue: stage tiles 0 and 1
  STAGE_NT(0, 0);
  if (nit > 1) STAGE_NT(1, 8192);

  for (int it = 0; it < nit; ++it) {
    const int base = (it % 3) * 8192;
    if (it + 1 < nit) asm volatile("s_waitcnt vmcnt(4)" ::: "memory");
    else              asm volatile("s_waitcnt vmcnt(0)" ::: "memory");
    __builtin_amdgcn_s_barrier();  // tile it fully landed for ALL waves

    if (it + 2 < nit) STAGE_NT(it + 2, ((it + 2) % 3) * 8192);

    const short* lA = &smem[base];
    const short* lB = &smem[base + 4096];
    short8 af[4], bf[4];
#pragma unroll
    for (int t = 0; t < 4; t++) {
      const int ra = wm * 64 + t * 16 + l16;
      const int rb = wn * 64 + t * 16 + l16;
      af[t] = *(const short8*)&lA[ra * 32 + ((quad ^ ((ra >> 1) & 3)) * 8)];
      bf[t] = *(const short8*)&lB[rb * 32 + ((quad ^ ((rb >> 1) & 3)) * 8)];
    }
    __builtin_amdgcn_s_setprio(1);
#pragma unroll
    for (int i = 0; i < 4; i++)
#pragma unroll
      for (int j = 0; j < 4; j++)
        acc[i][j] = mfma16x16x32(af[i], bf[j], acc[i][j]);
    __builtin_amdgcn_s_setprio(0);
  }
#undef STAGE_NT

  const int cm = wm * 64 + quad * 4;
  const int cn = wn * 64 + l16;
  if (OUT_F32) {
    float* Cf = (float*)C;
#pragma unroll
    for (int i = 0; i < 4; i++)
#pragma unroll
      for (int j = 0; j < 4; j++) {
        const long gn = n0 + cn + j * 16;
#pragma unroll
        for (int r = 0; r < 4; r++)
          Cf[(m0 + cm + i * 16 + r) * (long)ldc + gn] = acc[i][j][r] * scale;
      }
  } else {
    short* Cs = (short*)C;
#pragma unroll
    for (int i = 0; i < 4; i++)
#pragma unroll
      for (int j = 0; j < 4; j++) {
        const long gn = n0 + cn + j * 16;
#pragma unroll
        for (int r = 0; r < 4; r++)
          Cs[(m0 + cm + i * 16 + r) * (long)ldc + gn] = f2bf(acc[i][j][r] * scale);
      }
  }
}

// ---------------- fused KV projection ----------------
// 8 waves role-split, TRIPLE-buffered LDS (72 KB), one barrier + counted
// vmcnt(3) per K-step, setprio around MFMA cluster. grid=(S/128,I/128,Bg).
__global__ __launch_bounds__(512, 4) void gemm_kv(
    const short* __restrict__ Wk, const short* __restrict__ Wv,
    const short* __restrict__ visT, long sV,
    short* __restrict__ kout, short* __restrict__ vout, long sKV) {
  __shared__ alignas(16) short smem[36864];
  const int tid = threadIdx.x;
  const int lane = tid & 63, w = tid >> 6;
  const int quad = lane >> 4, l16 = lane & 15;
  const int role = w >> 2;          // 0 = k, 1 = v
  const int wq = w & 3, wm = wq >> 1, wn = wq & 1;
  const long n0 = (long)blockIdx.x * 128;  // s
  const long m0 = (long)blockIdx.y * 128;  // i
  const short* vis = visT + blockIdx.z * sV;
  short* kz = kout + blockIdx.z * sKV;
  short* vz = vout + blockIdx.z * sKV;

  float4v acc[4][4];
#pragma unroll
  for (int i = 0; i < 4; i++)
#pragma unroll
    for (int j = 0; j < 4; j++) acc[i][j] = (float4v)0.0f;

  const int srow = tid >> 2;  // 0..127
  const int scol = (((tid & 3) ^ ((srow >> 1) & 3))) * 8;  // swizzled source chunk

  const short* gWk = &Wk[(m0 + srow) * 512 + scol];
  const short* gWv = &Wv[(m0 + srow) * 512 + scol];
  const short* gV = &vis[(n0 + srow) * 512 + scol];

#define STAGE_KV(t, base)                                      \
  do {                                                         \
    load_lds16(gWk + (t) * 32, &smem[(base) + tid * 8]);       \
    load_lds16(gWv + (t) * 32, &smem[(base) + 4096 + tid * 8]);\
    load_lds16(gV + (t) * 32, &smem[(base) + 8192 + tid * 8]); \
  } while (0)

  // prologue: stage tiles 0 and 1 (tile 2 staged inside iter 0)
  STAGE_KV(0, 0);
  STAGE_KV(1, 12288);

  for (int it = 0; it < 16; ++it) {
    const int base = (it % 3) * 12288;
    if (it < 15) asm volatile("s_waitcnt vmcnt(3)" ::: "memory");
    else         asm volatile("s_waitcnt vmcnt(0)" ::: "memory");
    __builtin_amdgcn_s_barrier();  // tile it fully landed for ALL waves

    if (it + 2 < 16) STAGE_KV(it + 2, ((it + 2) % 3) * 12288);

    const short* lW = &smem[base + (role ? 4096 : 0)];
    const short* lVis = &smem[base + 8192];
    short8 af[4], bf[4];
#pragma unroll
    for (int t = 0; t < 4; t++) {
      const int ra = wm * 64 + t * 16 + l16;
      const int rb = wn * 64 + t * 16 + l16;
      af[t] = *(const short8*)&lW[ra * 32 + ((quad ^ ((ra >> 1) & 3)) * 8)];
      bf[t] = *(const short8*)&lVis[rb * 32 + ((quad ^ ((rb >> 1) & 3)) * 8)];
    }
    __builtin_amdgcn_s_setprio(1);
#pragma unroll
    for (int i = 0; i < 4; i++)
#pragma unroll
      for (int j = 0; j < 4; j++)
        acc[i][j] = mfma16x16x32(af[i], bf[j], acc[i][j]);
    __builtin_amdgcn_s_setprio(0);
  }
#undef STAGE_KV

  // C/D layout: col(n=s) = lane&15, row(m=i) = quad*4 + reg
  const int cm = wm * 64 + quad * 4;
  const int cn = wn * 64 + l16;

  // v: direct store (i,s)
  if (role == 1) {
#pragma unroll
    for (int i = 0; i < 4; i++)
#pragma unroll
      for (int j = 0; j < 4; j++) {
        const long gn = n0 + cn + j * 16;
#pragma unroll
        for (int r = 0; r < 4; r++)
          vz[(m0 + cm + i * 16 + r) * 4096 + gn] = f2bf(acc[i][j][r]);
      }
  }

  // k: retile through LDS -> coalesced 256B stores of k[s][i]
  short* scratch = smem;  // 64 rows x 136 shorts = 8704 <= 36864
#pragma unroll
  for (int h = 0; h < 2; h++) {
    __syncthreads();
    if (role == 0 && wn == h) {
#pragma unroll
      for (int j = 0; j < 4; j++)
#pragma unroll
        for (int i = 0; i < 4; i++) {
          const int nloc = j * 16 + l16;
          const int m = wm * 64 + i * 16 + quad * 4;
          short4v pk;
#pragma unroll
          for (int r = 0; r < 4; r++) pk[r] = f2bf(acc[i][j][r]);
          *(short4v*)&scratch[nloc * 136 + m] = pk;
        }
    }
    __syncthreads();
    {
      // drain full 64 x 128 tile: 512 threads x 16 shorts
      const int row = tid >> 3;        // 0..63
      const int off = (tid & 7) * 16;  // 0..112
      short8 v0 = *(const short8*)&scratch[row * 136 + off];
      short8 v1 = *(const short8*)&scratch[row * 136 + off + 8];
      *(short8*)&kz[(n0 + h * 64 + row) * 512 + m0 + off] = v0;
      *(short8*)&kz[(n0 + h * 64 + row) * 512 + m0 + off + 8] = v1;
    }
  }
}

// ---------------- vis fp32 (b,c,s) -> visT bf16 (b,s,c) ----------------
__global__ __launch_bounds__(256) void transpose_f2b(
    const float* __restrict__ vis, short* __restrict__ visT) {
  __shared__ alignas(16) short buf[64][68];
  const int tid = threadIdx.x;
  const long bz = blockIdx.z;
  const long s0 = (long)blockIdx.x * 64;
  const long c0 = (long)blockIdx.y * 64;
  const float* src = vis + bz * 512 * 4096;
  short* dst = visT + bz * 4096 * 512;
  const int tr = tid >> 4;
  const int tc4 = (tid & 15) * 4;
#pragma unroll
  for (int i = 0; i < 4; i++) {
    const int c = tr + i * 16;
    float4v val = *(const float4v*)&src[(c0 + c) * 4096 + s0 + tc4];
    buf[tc4 + 0][c] = f2bf(val[0]);
    buf[tc4 + 1][c] = f2bf(val[1]);
    buf[tc4 + 2][c] = f2bf(val[2]);
    buf[tc4 + 3][c] = f2bf(val[3]);
  }
  __syncthreads();
#pragma unroll
  for (int i = 0; i < 4; i++) {
    const int s = tr + i * 16;
    short4v val = *(const short4v*)&buf[s][tc4];
    *(short4v*)&dst[(s0 + s) * 512 + c0 + tc4] = val;
  }
}

// ---------------- attention partial: block = (head, batch, s-chunk) ----------------
// v5: SWAPPED QK^T — sc_T = mfma(K_frag, Q_frag) puts C rows = s, cols = t,
// so each lane holds 4 CONSECUTIVE s-values for one t-column. The P-park into
// lp[t][s] (same layout/swizzle the PV loop already reads) becomes one packed
// ds_write_b64 per 4 values (cvt_pk_bf16 pairs) instead of 32 scalar
// ds_write_u16 per thread. Row sums are lane-local per t; one xor16+xor32
// shuffle pair at the end. PV loop, staging, and barriers are unchanged.
__global__ __launch_bounds__(256) void attn_part(
    const short* __restrict__ q, const short* __restrict__ kws,
    const short* __restrict__ vws, float* __restrict__ Opart,
    float* __restrict__ lpart, int b0) {
  const int h = blockIdx.x;
  const int bz = blockIdx.y;
  const int ch = blockIdx.z;
  const int tid = threadIdx.x;
  const int lane = tid & 63, w = tid >> 6;
  const int quad = lane >> 4, l16 = lane & 15;

  __shared__ alignas(16) short lq[64 * 64];
  __shared__ alignas(16) short lk[128 * 64];
  __shared__ alignas(16) short lv[64 * 128];
  __shared__ alignas(16) short lp[64 * 128];
  __shared__ float lsum[64];

  const short* qb = q + ((long)(b0 + bz) * 64) * 512 + h * 64;
  const short* kb = kws + (long)bz * 4096 * 512 + h * 64;
  const short* vb = vws + (long)bz * 512 * 4096 + (long)h * 64 * 4096;

  if (tid < 64) lsum[tid] = 0.0f;
  {
    // lq: 64 rows x 8 chunks; slot (r, c) <- global chunk c ^ (r&7)
    const int qr = tid >> 3;
    const int qc = ((tid & 7) ^ (qr & 7)) * 8;
    load_lds16(&qb[qr * 512 + qc], &lq[tid * 8]);
    load_lds16(&qb[(32 + qr) * 512 + qc], &lq[2048 + tid * 8]);  // (32+qr)&7 == qr&7
  }
  // prologue: stage first k/v chunk (overlaps q fragment setup)
  const int s0_first = ch * (4096 / NCH);
  const int send = s0_first + (4096 / NCH);
#pragma unroll
  for (int it = 0; it < 4; it++) {
    const int li = tid + it * 256;
    const int kr = li >> 3;
    const int kc = ((li & 7) ^ (kr & 7)) * 8;
    load_lds16(&kb[(long)(s0_first + kr) * 512 + kc], &lk[li * 8]);
  }
#pragma unroll
  for (int it = 0; it < 4; it++) {
    const int li = tid + it * 256;
    const int vr = li >> 4;
    const int vc = ((li & 15) ^ (vr & 7)) * 8;
    load_lds16(&vb[(long)vr * 4096 + s0_first + vc], &lv[li * 8]);
  }
  __syncthreads();  // lq + first k/v landed

  short8 aq[4][2];
#pragma unroll
  for (int mt = 0; mt < 4; mt++)
#pragma unroll
    for (int ks = 0; ks < 2; ks++) {
      const int ra = mt * 16 + l16;
      aq[mt][ks] = *(const short8*)&lq[ra * 64 + (((ks * 4 + quad) ^ (ra & 7)) * 8)];
    }

  float4v osc[4];
#pragma unroll
  for (int mt = 0; mt < 4; mt++) osc[mt] = (float4v)0.0f;
  float lrow[4] = {0.0f, 0.0f, 0.0f, 0.0f};  // per tj (t = tj*16 + l16)

  // P-write addressing: lane (quad,l16) of wave w holds, per (si,tj),
  // s = w*32 + si*16 + quad*4 + r  (4 consecutive), t = tj*16 + l16.
  const int cbase = w * 4 + (quad >> 1);  // s-chunk index (+ si*2)
  const int sub = (quad & 1) * 4;         // short offset within 8-chunk

  for (int s0 = s0_first; s0 < send; s0 += 128) {
    // pull ALL lk/lv fragments for this chunk into regs
    short8 bk[2][2];  // [ks][si]
#pragma unroll
    for (int ks = 0; ks < 2; ks++)
#pragma unroll
      for (int si = 0; si < 2; si++) {
        const int rb = (2 * w + si) * 16 + l16;
        bk[ks][si] = *(const short8*)&lk[rb * 64 + (((ks * 4 + quad) ^ (rb & 7)) * 8)];
      }
    short8 bv[4];
#pragma unroll
    for (int ks = 0; ks < 4; ks++) {
      const int rv = w * 16 + l16;
      bv[ks] = *(const short8*)&lv[rv * 128 + (((ks * 4 + quad) ^ (rv & 7)) * 8)];
    }
    __syncthreads();  // all waves done with lk/lv (also drains prior staging)

    if (s0 + 128 < send) {  // stage next chunk; overlaps QK+softmax+PV
#pragma unroll
      for (int it = 0; it < 4; it++) {
        const int li = tid + it * 256;
        const int kr = li >> 3;
        const int kc = ((li & 7) ^ (kr & 7)) * 8;
        load_lds16(&kb[(long)(s0 + 128 + kr) * 512 + kc], &lk[li * 8]);
      }
#pragma unroll
      for (int it = 0; it < 4; it++) {
        const int li = tid + it * 256;
        const int vr = li >> 4;
        const int vc = ((li & 15) ^ (vr & 7)) * 8;
        load_lds16(&vb[(long)vr * 4096 + s0 + 128 + vc], &lv[li * 8]);
      }
    }

    // scores TRANSPOSED: sc[si][tj] has rows = s, cols = t.
    float4v sc[2][4];
#pragma unroll
    for (int si = 0; si < 2; si++)
#pragma unroll
      for (int tj = 0; tj < 4; tj++) sc[si][tj] = (float4v)0.0f;
#pragma unroll
    for (int ks = 0; ks < 2; ks++)
#pragma unroll
      for (int si = 0; si < 2; si++)
#pragma unroll
        for (int tj = 0; tj < 4; tj++)
          sc[si][tj] = mfma16x16x32(bk[ks][si], aq[tj][ks], sc[si][tj]);

    // softmax: p = exp(clamped score); pack 4 consecutive s as 2x cvt_pk ->
    // one b64 write into lp[t][s] (chunk-XOR swizzle, same as PV read).
#pragma unroll
    for (int si = 0; si < 2; si++) {
      const int c = cbase + si * 2;
#pragma unroll
      for (int tj = 0; tj < 4; tj++) {
        float p0 = __expf(fminf(fmaxf(sc[si][tj][0], -80.0f), 30.0f));
        float p1 = __expf(fminf(fmaxf(sc[si][tj][1], -80.0f), 30.0f));
        float p2 = __expf(fminf(fmaxf(sc[si][tj][2], -80.0f), 30.0f));
        float p3 = __expf(fminf(fmaxf(sc[si][tj][3], -80.0f), 30.0f));
        const uint32_t u01 = cvt_pk_bf16(p0, p1);
        const uint32_t u23 = cvt_pk_bf16(p2, p3);
        // accumulate the bf16-QUANTIZED values (keeps num/denom consistent)
        lrow[tj] += __builtin_bit_cast(float, u01 << 16) +
                    __builtin_bit_cast(float, u01 & 0xffff0000u) +
                    __builtin_bit_cast(float, u23 << 16) +
                    __builtin_bit_cast(float, u23 & 0xffff0000u);
        const int t = tj * 16 + l16;
        uint2v val; val.x = u01; val.y = u23;
        *(uint2v*)&lp[t * 128 + ((c ^ (t & 7)) * 8) + sub] = val;
      }
    }
    // lp ready: raw barrier — k/v staging must STAY in flight through PV
    asm volatile("s_waitcnt lgkmcnt(0)" ::: "memory");
    __builtin_amdgcn_sched_barrier(0);
    __builtin_amdgcn_s_barrier();

    // PV from lp (this-iter data) and bv regs — unchanged
#pragma unroll
    for (int ks = 0; ks < 4; ks++)
#pragma unroll
      for (int mt = 0; mt < 4; mt++) {
        const int rp = mt * 16 + l16;
        const short8 ap = *(const short8*)&lp[rp * 128 + (((ks * 4 + quad) ^ (rp & 7)) * 8)];
        osc[mt] = mfma16x16x32(ap, bv[ks], osc[mt]);
      }
    __syncthreads();  // everyone done with lp; staging drains before next frag reads
  }

  // row-sum reduce: lane holds per-t partials over its s-share; fold quads.
#pragma unroll
  for (int tj = 0; tj < 4; tj++) {
    float v = lrow[tj];
    v += __shfl_xor(v, 16);
    v += __shfl_xor(v, 32);
    if (quad == 0) atomicAdd(&lsum[tj * 16 + l16], v);
  }
  __syncthreads();

  const long bh = bz * 8 + h;
  float* op = Opart + ((bh * NCH + ch) * 64) * 64 + w * 16 + l16;
#pragma unroll
  for (int mt = 0; mt < 4; mt++)
#pragma unroll
    for (int r = 0; r < 4; r++)
      op[(long)(mt * 16 + quad * 4 + r) * 64] = osc[mt][r];
  if (tid < 64) lpart[(bh * NCH + ch) * 64 + tid] = lsum[tid];
}

// ---------------- combine attention partials -> tmp bf16 (b,t,i) ----------------
// v2: 4-wide vectorized (float4 reads of Opart, short4 writes of tmp).
__global__ __launch_bounds__(256) void attn_combine(
    const float* __restrict__ Opart, const float* __restrict__ lpart,
    short* __restrict__ tmp, int b0, int nbh) {
  const int total4 = nbh * 1024;  // groups of 4 consecutive d
  for (int i4 = blockIdx.x * 256 + threadIdx.x; i4 < total4;
       i4 += gridDim.x * 256) {
    const int bh = i4 >> 10;
    const int td = (i4 & 1023) << 2;  // multiple of 4; same t for all 4
    const int t = td >> 6;
    float4v o = (float4v)0.0f;
    float l = 0.0f;
#pragma unroll
    for (int c = 0; c < NCH; c++) {
      o += *(const float4v*)&Opart[(((long)bh * NCH + c) << 12) + td];
      l += lpart[(bh * NCH + c) * 64 + t];
    }
    const float inv = 1.0f / l;
    const int b = b0 + (bh >> 3), h = bh & 7;
    short4v r;
#pragma unroll
    for (int j = 0; j < 4; j++) r[j] = f2bf(o[j] * inv);
    *(short4v*)&tmp[((long)b * 64 + t) * 512 + h * 64 + (td & 63)] = r;
  }
}

// ---------------- launch ----------------
extern "C" void kernel_launch(void* const* d_in, const int* in_sizes, int n_in,
                              void* d_out, int out_size, void* d_ws, size_t ws_size,
                              hipStream_t stream) {
  (void)in_sizes; (void)n_in; (void)out_size;
  const float* vis = (const float*)d_in[0];   // [16][512][4096] fp32
  const float* lang = (const float*)d_in[1];  // [16][64][512]  fp32
  const float* Wq = (const float*)d_in[3];    // [512][512] fp32
  const float* Wk = (const float*)d_in[4];
  const float* Wv = (const float*)d_in[5];
  const float* Wo = (const float*)d_in[6];
  float* out = (float*)d_out;                 // [16][64][512] fp32

  char* ws = (char*)d_ws;
  const size_t MB = 1 << 20;
  short* q_ws = (short*)(ws + 0 * MB);
  short* tmp_ws = (short*)(ws + 1 * MB);
  short* langb = (short*)(ws + 2 * MB);
  short* Wqb = (short*)(ws + 3 * MB);
  short* Wkb = (short*)(ws + 3 * MB + 512 * 1024);
  short* Wvb = (short*)(ws + 4 * MB);
  short* Wob = (short*)(ws + 4 * MB + 512 * 1024);
  char* grp = ws + 5 * MB;

  const long batch_elems = 4096l * 512;
  int g = 16;
  const int cands[5] = {1, 2, 4, 8, 16};
  for (int ci = 0; ci < 5; ci++) {
    const size_t need = 5 * MB + 3ull * (16 / cands[ci]) * batch_elems * 2;
    if (need <= ws_size) { g = cands[ci]; break; }
  }
  const int Bg = 16 / g;
  short* visT = (short*)grp;                    // [Bg][4096][512]
  short* k_ws = visT + (long)Bg * batch_elems;  // [Bg][4096][512] (s,i)
  short* v_ws = k_ws + (long)Bg * batch_elems;  // [Bg][512][4096] (i,s)
  // attn partials alias visT (dead by attn time)
  float* Opart = (float*)visT;
  float* lptr = Opart + (long)Bg * 8 * NCH * 4096;

  convert5<<<dim3(128, 5), 256, 0, stream>>>(lang, langb, Wq, Wqb, Wk, Wkb,
                                             Wv, Wvb, Wo, Wob);

  // q = SCALE * lang @ Wq^T
  gemm_nt<0><<<dim3(4, 8), 256, 0, stream>>>(langb, Wqb, q_ws, 512, 512, 0.125f);

  for (int gi = 0; gi < g; gi++) {
    const int b0 = gi * Bg;
    transpose_f2b<<<dim3(64, 8, Bg), 256, 0, stream>>>(vis + (long)b0 * batch_elems, visT);
    gemm_kv<<<dim3(32, 4, Bg), 512, 0, stream>>>(Wkb, Wvb, visT, batch_elems,
                                                 k_ws, v_ws, batch_elems);
    attn_part<<<dim3(8, Bg, NCH), 256, 0, stream>>>(q_ws, k_ws, v_ws, Opart, lptr, b0);
    attn_combine<<<512, 256, 0, stream>>>(Opart, lptr, tmp_ws, b0, Bg * 8);
  }

  // out = tmp @ Wo^T, fp32 epilogue
  gemm_nt<1><<<dim3(4, 8), 256, 0, stream>>>(tmp_ws, Wob, out, 512, 512, 1.0f);
}

// Round 8
// 327.892 us; speedup vs baseline: 1.1574x; 1.0109x over previous
//
#include <hip/hip_runtime.h>
#include <stdint.h>

// ---------------- common helpers ----------------
typedef __attribute__((ext_vector_type(8))) short short8;
typedef __attribute__((ext_vector_type(4))) short short4v;
typedef __attribute__((ext_vector_type(4))) float float4v;
typedef __attribute__((ext_vector_type(2))) unsigned int uint2v;
typedef __attribute__((ext_vector_type(4))) unsigned int uint4v;
typedef __attribute__((ext_vector_type(8))) __bf16 bf16x8;

#define NCH 4  // attention S-dim split factor

__device__ __forceinline__ float4v mfma16x16x32(short8 a, short8 b, float4v c) {
  return __builtin_amdgcn_mfma_f32_16x16x32_bf16(
      __builtin_bit_cast(bf16x8, a), __builtin_bit_cast(bf16x8, b), c, 0, 0, 0);
}

// float -> bf16 (RNE), as raw short
__device__ __forceinline__ short f2bf(float f) {
  uint32_t u = __builtin_bit_cast(uint32_t, f);
  u += 0x7fffu + ((u >> 16) & 1u);
  return (short)(u >> 16);
}

__device__ __forceinline__ float bf2f(short s) {
  return __builtin_bit_cast(float, ((uint32_t)(uint16_t)s) << 16);
}

// pack two f32 -> two bf16 (RNE) in one u32 (lo = a, hi = b)
__device__ __forceinline__ uint32_t cvt_pk_bf16(float a, float b) {
  uint32_t r;
  asm("v_cvt_pk_bf16_f32 %0, %1, %2" : "=v"(r) : "v"(a), "v"(b));
  return r;
}

// async 16B global->LDS. LDS dst = wave-uniform base + lane*16 at all sites.
__device__ __forceinline__ void load_lds16(const short* g, short* l) {
  __builtin_amdgcn_global_load_lds(
      (const __attribute__((address_space(1))) void*)g,
      (__attribute__((address_space(3))) void*)l, 16, 0, 0);
}

// ---------------- fused fp32 -> bf16 for lang + 4 weights ----------------
__global__ __launch_bounds__(256) void convert5(
    const float* __restrict__ sl, short* __restrict__ dl,
    const float* __restrict__ s1, short* __restrict__ d1,
    const float* __restrict__ s2, short* __restrict__ d2,
    const float* __restrict__ s3, short* __restrict__ d3,
    const float* __restrict__ s4, short* __restrict__ d4) {
  const float* src; short* dst; int n4;
  switch (blockIdx.y) {
    case 0: src = sl; dst = dl; n4 = 131072; break;
    case 1: src = s1; dst = d1; n4 = 65536; break;
    case 2: src = s2; dst = d2; n4 = 65536; break;
    case 3: src = s3; dst = d3; n4 = 65536; break;
    default: src = s4; dst = d4; n4 = 65536; break;
  }
  const int stride = gridDim.x * blockDim.x;
  for (int i = blockIdx.x * blockDim.x + threadIdx.x; i < n4; i += stride) {
    float4v v = *(const float4v*)(src + (long)i * 4);
    short4v o;
#pragma unroll
    for (int r = 0; r < 4; r++) o[r] = f2bf(v[r]);
    *(short4v*)(dst + (long)i * 4) = o;
  }
}

// ---------------- small NT GEMM (q / out projections) ----------------
// C[m,n] = scale * sum_k A[m,k]*B[n,k]; 128x128 tile, BK=32, 4 waves.
// TRIPLE-buffered LDS, ONE barrier + one counted vmcnt per K-step.
template <int OUT_F32>
__global__ __launch_bounds__(256) void gemm_nt(
    const short* __restrict__ A, const short* __restrict__ B,
    void* __restrict__ C, int K, int ldc, float scale) {
  __shared__ alignas(16) short smem[24576];  // 3 x (lA 4096 | lB 4096) shorts
  const int tid = threadIdx.x;
  const int lane = tid & 63, w = tid >> 6;
  const int quad = lane >> 4, l16 = lane & 15;
  const int wm = w >> 1, wn = w & 1;
  const long m0 = (long)blockIdx.y * 128, n0 = (long)blockIdx.x * 128;

  float4v acc[4][4];
#pragma unroll
  for (int i = 0; i < 4; i++)
#pragma unroll
    for (int j = 0; j < 4; j++) acc[i][j] = (float4v)0.0f;

  const int srow = tid >> 2;  // 0..63 (also used at +64)
  const int scol = (((tid & 3) ^ ((srow >> 1) & 3))) * 8;  // swizzled source chunk
  const int nit = K >> 5;

#define STAGE_NT(t, base)                                                       \
  do {                                                                          \
    load_lds16(&A[(m0 + srow) * K + (t) * 32 + scol], &smem[(base) + tid * 8]); \
    load_lds16(&A[(m0 + 64 + srow) * K + (t) * 32 + scol],                      \
               &smem[(base) + 2048 + tid * 8]);                                 \
    load_lds16(&B[(n0 + srow) * K + (t) * 32 + scol],                           \
               &smem[(base) + 4096 + tid * 8]);                                 \
    load_lds16(&B[(n0 + 64 + srow) * K + (t) * 32 + scol],                      \
               &smem[(base) + 6144 + tid * 8]);                                 \
  } while (0)

  // prologue: stage tiles 0 and 1
  STAGE_NT(0, 0);
  if (nit > 1) STAGE_NT(1, 8192);

  for (int it = 0; it < nit; ++it) {
    const int base = (it % 3) * 8192;
    if (it + 1 < nit) asm volatile("s_waitcnt vmcnt(4)" ::: "memory");
    else              asm volatile("s_waitcnt vmcnt(0)" ::: "memory");
    __builtin_amdgcn_s_barrier();  // tile it fully landed for ALL waves

    if (it + 2 < nit) STAGE_NT(it + 2, ((it + 2) % 3) * 8192);

    const short* lA = &smem[base];
    const short* lB = &smem[base + 4096];
    short8 af[4], bf[4];
#pragma unroll
    for (int t = 0; t < 4; t++) {
      const int ra = wm * 64 + t * 16 + l16;
      const int rb = wn * 64 + t * 16 + l16;
      af[t] = *(const short8*)&lA[ra * 32 + ((quad ^ ((ra >> 1) & 3)) * 8)];
      bf[t] = *(const short8*)&lB[rb * 32 + ((quad ^ ((rb >> 1) & 3)) * 8)];
    }
    __builtin_amdgcn_s_setprio(1);
#pragma unroll
    for (int i = 0; i < 4; i++)
#pragma unroll
      for (int j = 0; j < 4; j++)
        acc[i][j] = mfma16x16x32(af[i], bf[j], acc[i][j]);
    __builtin_amdgcn_s_setprio(0);
  }
#undef STAGE_NT

  const int cm = wm * 64 + quad * 4;
  const int cn = wn * 64 + l16;
  if (OUT_F32) {
    float* Cf = (float*)C;
#pragma unroll
    for (int i = 0; i < 4; i++)
#pragma unroll
      for (int j = 0; j < 4; j++) {
        const long gn = n0 + cn + j * 16;
#pragma unroll
        for (int r = 0; r < 4; r++)
          Cf[(m0 + cm + i * 16 + r) * (long)ldc + gn] = acc[i][j][r] * scale;
      }
  } else {
    short* Cs = (short*)C;
#pragma unroll
    for (int i = 0; i < 4; i++)
#pragma unroll
      for (int j = 0; j < 4; j++) {
        const long gn = n0 + cn + j * 16;
#pragma unroll
        for (int r = 0; r < 4; r++)
          Cs[(m0 + cm + i * 16 + r) * (long)ldc + gn] = f2bf(acc[i][j][r] * scale);
      }
  }
}

// ---------------- fused KV projection, fp32-vis direct ----------------
// v8: consumes vis fp32 (c,s) directly (transpose_f2b deleted), but with
// VERIFIED primitives only — no tr_b16 (v6/v7's identical absmax proved the
// tr-read semantic model wrong, not a race). vis staging: thread
// (sl=tid&127, oct=tid>>7) does 8 coalesced scalar float loads (per wave:
// 64 consecutive s at fixed c = 256B/instr), cvt_pk x4, ONE ds_write_b128
// at sl*32 + ((oct ^ ((sl>>1)&3))*8) — the EXACT XOR-swizzled layout the
// verified b128 fragment reads already use. Frag reads + MFMA loop are
// byte-identical to the 84.6us R4 kernel.
// vmcnt ledger (sched_barrier pins vis-loads older than W-gloads):
// per tile issues [vis x8, W x2]; top-of-body vmcnt(2) completes
// {vis(it+1)->regs, W(it)->LDS}, leaves W(it+1) flying. VWRITE(it+1)
// pre-barrier, own ds_writes drained by lgkmcnt(0). Triple buffer makes
// writer/reader separated by >= one barrier (same argument as R4).
// LDS: 3 x (Wk 8KB | Wv 8KB | vis 8KB) = 72 KB, 2 blocks/CU.
__global__ __launch_bounds__(512, 4) void gemm_kv(
    const short* __restrict__ Wk, const short* __restrict__ Wv,
    const float* __restrict__ visf, long sV,
    short* __restrict__ kout, short* __restrict__ vout, long sKV) {
  __shared__ alignas(16) short smem[36864];
  const int tid = threadIdx.x;
  const int lane = tid & 63, w = tid >> 6;
  const int quad = lane >> 4, l16 = lane & 15;
  const int role = w >> 2;          // 0 = k, 1 = v
  const int wq = w & 3, wm = wq >> 1, wn = wq & 1;
  const long n0 = (long)blockIdx.x * 128;  // s
  const long m0 = (long)blockIdx.y * 128;  // i
  const float* vis = visf + blockIdx.z * sV;
  short* kz = kout + blockIdx.z * sKV;
  short* vz = vout + blockIdx.z * sKV;

  float4v acc[4][4];
#pragma unroll
  for (int i = 0; i < 4; i++)
#pragma unroll
    for (int j = 0; j < 4; j++) acc[i][j] = (float4v)0.0f;

  // W staging (unchanged XOR-swizzled layout, global_load_lds)
  const int srow = tid >> 2;  // 0..127
  const int scol = (((tid & 3) ^ ((srow >> 1) & 3))) * 8;
  const short* gWk = &Wk[(m0 + srow) * 512 + scol];
  const short* gWv = &Wv[(m0 + srow) * 512 + scol];

  // vis staging: thread covers row sl (s-local), channel octet oct
  const int sl = tid & 127;
  const int oct = tid >> 7;  // 0..3
  const float* gv = vis + (long)(oct * 8) * 4096 + n0 + sl;
  const int woff = 8192 + sl * 32 + ((oct ^ ((sl >> 1) & 3)) * 8);

#define STAGE_W(t, base)                                          \
  do {                                                            \
    load_lds16(gWk + (t) * 32, &smem[(base) + tid * 8]);          \
    load_lds16(gWv + (t) * 32, &smem[(base) + 4096 + tid * 8]);   \
  } while (0)

#define VLOAD(t)                                                  \
  do {                                                            \
    _Pragma("unroll")                                             \
    for (int j = 0; j < 8; j++)                                   \
      vf[j] = gv[((t) * 32 + j) * 4096];                          \
  } while (0)

#define VWRITE(base)                                              \
  do {                                                            \
    uint4v pw;                                                    \
    pw.x = cvt_pk_bf16(vf[0], vf[1]);                             \
    pw.y = cvt_pk_bf16(vf[2], vf[3]);                             \
    pw.z = cvt_pk_bf16(vf[4], vf[5]);                             \
    pw.w = cvt_pk_bf16(vf[6], vf[7]);                             \
    *(uint4v*)&smem[(base) + woff] = pw;                          \
  } while (0)

  float vf[8];
  // prologue: vis(0) -> regs -> buf0; then vis(1), W(0), W(1) in flight
  VLOAD(0);
  asm volatile("s_waitcnt vmcnt(0)" ::: "memory");
  VWRITE(0);
  VLOAD(1);
  __builtin_amdgcn_sched_barrier(0);  // vis loads stay OLDER than W gloads
  STAGE_W(0, 0);
  STAGE_W(1, 12288);

  for (int it = 0; it < 16; ++it) {
    const int base = (it % 3) * 12288;
    // completes vis(it+1)->regs + W(it)->LDS; leaves W(it+1) flying
    if (it < 15) asm volatile("s_waitcnt vmcnt(2)" ::: "memory");
    else         asm volatile("s_waitcnt vmcnt(0)" ::: "memory");
    if (it < 15) VWRITE(((it + 1) % 3) * 12288);  // vis(it+1) -> LDS
    asm volatile("s_waitcnt lgkmcnt(0)" ::: "memory");  // drain own ds_writes
    __builtin_amdgcn_s_barrier();  // publishes W(it) + vis(it)

    if (it + 2 < 16) {
      VLOAD(it + 2);
      __builtin_amdgcn_sched_barrier(0);  // vis loads issue before W gloads
      STAGE_W(it + 2, ((it + 2) % 3) * 12288);
    }

    // fragment reads + MFMA: byte-identical to the verified R4 kernel
    const short* lW = &smem[base + (role ? 4096 : 0)];
    const short* lVis = &smem[base + 8192];
    short8 af[4], bf[4];
#pragma unroll
    for (int t = 0; t < 4; t++) {
      const int ra = wm * 64 + t * 16 + l16;
      const int rb = wn * 64 + t * 16 + l16;
      af[t] = *(const short8*)&lW[ra * 32 + ((quad ^ ((ra >> 1) & 3)) * 8)];
      bf[t] = *(const short8*)&lVis[rb * 32 + ((quad ^ ((rb >> 1) & 3)) * 8)];
    }
    __builtin_amdgcn_s_setprio(1);
#pragma unroll
    for (int i = 0; i < 4; i++)
#pragma unroll
      for (int j = 0; j < 4; j++)
        acc[i][j] = mfma16x16x32(af[i], bf[j], acc[i][j]);
    __builtin_amdgcn_s_setprio(0);
  }
#undef STAGE_W
#undef VLOAD
#undef VWRITE

  // C/D layout: col(n=s) = lane&15, row(m=i) = quad*4 + reg
  const int cm = wm * 64 + quad * 4;
  const int cn = wn * 64 + l16;

  // v: direct store (i,s)
  if (role == 1) {
#pragma unroll
    for (int i = 0; i < 4; i++)
#pragma unroll
      for (int j = 0; j < 4; j++) {
        const long gn = n0 + cn + j * 16;
#pragma unroll
        for (int r = 0; r < 4; r++)
          vz[(m0 + cm + i * 16 + r) * 4096 + gn] = f2bf(acc[i][j][r]);
      }
  }

  // k: retile through LDS -> coalesced 256B stores of k[s][i]
  short* scratch = smem;  // 64 rows x 136 shorts = 8704 <= 36864
#pragma unroll
  for (int h = 0; h < 2; h++) {
    __syncthreads();
    if (role == 0 && wn == h) {
#pragma unroll
      for (int j = 0; j < 4; j++)
#pragma unroll
        for (int i = 0; i < 4; i++) {
          const int nloc = j * 16 + l16;
          const int m = wm * 64 + i * 16 + quad * 4;
          short4v pk;
#pragma unroll
          for (int r = 0; r < 4; r++) pk[r] = f2bf(acc[i][j][r]);
          *(short4v*)&scratch[nloc * 136 + m] = pk;
        }
    }
    __syncthreads();
    {
      // drain full 64 x 128 tile: 512 threads x 16 shorts
      const int row = tid >> 3;        // 0..63
      const int off = (tid & 7) * 16;  // 0..112
      short8 v0 = *(const short8*)&scratch[row * 136 + off];
      short8 v1 = *(const short8*)&scratch[row * 136 + off + 8];
      *(short8*)&kz[(n0 + h * 64 + row) * 512 + m0 + off] = v0;
      *(short8*)&kz[(n0 + h * 64 + row) * 512 + m0 + off + 8] = v1;
    }
  }
}

// ---------------- attention partial: block = (head, batch, s-chunk) ----------------
// Swapped QK^T (sc rows = s, cols = t): packed b64 P-writes into lp[t][s];
// k/v frag reads hoisted to regs; staging stays in flight through PV.
// (Verified at R5: absmax 0.00146.)
__global__ __launch_bounds__(256) void attn_part(
    const short* __restrict__ q, const short* __restrict__ kws,
    const short* __restrict__ vws, float* __restrict__ Opart,
    float* __restrict__ lpart, int b0) {
  const int h = blockIdx.x;
  const int bz = blockIdx.y;
  const int ch = blockIdx.z;
  const int tid = threadIdx.x;
  const int lane = tid & 63, w = tid >> 6;
  const int quad = lane >> 4, l16 = lane & 15;

  __shared__ alignas(16) short lq[64 * 64];
  __shared__ alignas(16) short lk[128 * 64];
  __shared__ alignas(16) short lv[64 * 128];
  __shared__ alignas(16) short lp[64 * 128];
  __shared__ float lsum[64];

  const short* qb = q + ((long)(b0 + bz) * 64) * 512 + h * 64;
  const short* kb = kws + (long)bz * 4096 * 512 + h * 64;
  const short* vb = vws + (long)bz * 512 * 4096 + (long)h * 64 * 4096;

  if (tid < 64) lsum[tid] = 0.0f;
  {
    // lq: 64 rows x 8 chunks; slot (r, c) <- global chunk c ^ (r&7)
    const int qr = tid >> 3;
    const int qc = ((tid & 7) ^ (qr & 7)) * 8;
    load_lds16(&qb[qr * 512 + qc], &lq[tid * 8]);
    load_lds16(&qb[(32 + qr) * 512 + qc], &lq[2048 + tid * 8]);  // (32+qr)&7 == qr&7
  }
  // prologue: stage first k/v chunk (overlaps q fragment setup)
  const int s0_first = ch * (4096 / NCH);
  const int send = s0_first + (4096 / NCH);
#pragma unroll
  for (int it = 0; it < 4; it++) {
    const int li = tid + it * 256;
    const int kr = li >> 3;
    const int kc = ((li & 7) ^ (kr & 7)) * 8;
    load_lds16(&kb[(long)(s0_first + kr) * 512 + kc], &lk[li * 8]);
  }
#pragma unroll
  for (int it = 0; it < 4; it++) {
    const int li = tid + it * 256;
    const int vr = li >> 4;
    const int vc = ((li & 15) ^ (vr & 7)) * 8;
    load_lds16(&vb[(long)vr * 4096 + s0_first + vc], &lv[li * 8]);
  }
  __syncthreads();  // lq + first k/v landed

  short8 aq[4][2];
#pragma unroll
  for (int mt = 0; mt < 4; mt++)
#pragma unroll
    for (int ks = 0; ks < 2; ks++) {
      const int ra = mt * 16 + l16;
      aq[mt][ks] = *(const short8*)&lq[ra * 64 + (((ks * 4 + quad) ^ (ra & 7)) * 8)];
    }

  float4v osc[4];
#pragma unroll
  for (int mt = 0; mt < 4; mt++) osc[mt] = (float4v)0.0f;
  float lrow[4] = {0.0f, 0.0f, 0.0f, 0.0f};  // per tj (t = tj*16 + l16)

  const int cbase = w * 4 + (quad >> 1);  // s-chunk index (+ si*2)
  const int sub = (quad & 1) * 4;         // short offset within 8-chunk

  for (int s0 = s0_first; s0 < send; s0 += 128) {
    // pull ALL lk/lv fragments for this chunk into regs
    short8 bk[2][2];  // [ks][si]
#pragma unroll
    for (int ks = 0; ks < 2; ks++)
#pragma unroll
      for (int si = 0; si < 2; si++) {
        const int rb = (2 * w + si) * 16 + l16;
        bk[ks][si] = *(const short8*)&lk[rb * 64 + (((ks * 4 + quad) ^ (rb & 7)) * 8)];
      }
    short8 bv[4];
#pragma unroll
    for (int ks = 0; ks < 4; ks++) {
      const int rv = w * 16 + l16;
      bv[ks] = *(const short8*)&lv[rv * 128 + (((ks * 4 + quad) ^ (rv & 7)) * 8)];
    }
    __syncthreads();  // all waves done with lk/lv (also drains prior staging)

    if (s0 + 128 < send) {  // stage next chunk; overlaps QK+softmax+PV
#pragma unroll
      for (int it = 0; it < 4; it++) {
        const int li = tid + it * 256;
        const int kr = li >> 3;
        const int kc = ((li & 7) ^ (kr & 7)) * 8;
        load_lds16(&kb[(long)(s0 + 128 + kr) * 512 + kc], &lk[li * 8]);
      }
#pragma unroll
      for (int it = 0; it < 4; it++) {
        const int li = tid + it * 256;
        const int vr = li >> 4;
        const int vc = ((li & 15) ^ (vr & 7)) * 8;
        load_lds16(&vb[(long)vr * 4096 + s0 + 128 + vc], &lv[li * 8]);
      }
    }

    // scores TRANSPOSED: sc[si][tj] has rows = s, cols = t.
    float4v sc[2][4];
#pragma unroll
    for (int si = 0; si < 2; si++)
#pragma unroll
      for (int tj = 0; tj < 4; tj++) sc[si][tj] = (float4v)0.0f;
#pragma unroll
    for (int ks = 0; ks < 2; ks++)
#pragma unroll
      for (int si = 0; si < 2; si++)
#pragma unroll
        for (int tj = 0; tj < 4; tj++)
          sc[si][tj] = mfma16x16x32(bk[ks][si], aq[tj][ks], sc[si][tj]);

    // softmax: p = exp(clamped score); pack 4 consecutive s -> one b64 write
#pragma unroll
    for (int si = 0; si < 2; si++) {
      const int c = cbase + si * 2;
#pragma unroll
      for (int tj = 0; tj < 4; tj++) {
        float p0 = __expf(fminf(fmaxf(sc[si][tj][0], -80.0f), 30.0f));
        float p1 = __expf(fminf(fmaxf(sc[si][tj][1], -80.0f), 30.0f));
        float p2 = __expf(fminf(fmaxf(sc[si][tj][2], -80.0f), 30.0f));
        float p3 = __expf(fminf(fmaxf(sc[si][tj][3], -80.0f), 30.0f));
        const uint32_t u01 = cvt_pk_bf16(p0, p1);
        const uint32_t u23 = cvt_pk_bf16(p2, p3);
        // accumulate the bf16-QUANTIZED values (keeps num/denom consistent)
        lrow[tj] += __builtin_bit_cast(float, u01 << 16) +
                    __builtin_bit_cast(float, u01 & 0xffff0000u) +
                    __builtin_bit_cast(float, u23 << 16) +
                    __builtin_bit_cast(float, u23 & 0xffff0000u);
        const int t = tj * 16 + l16;
        uint2v val; val.x = u01; val.y = u23;
        *(uint2v*)&lp[t * 128 + ((c ^ (t & 7)) * 8) + sub] = val;
      }
    }
    // lp ready: raw barrier — k/v staging must STAY in flight through PV
    asm volatile("s_waitcnt lgkmcnt(0)" ::: "memory");
    __builtin_amdgcn_sched_barrier(0);
    __builtin_amdgcn_s_barrier();

    // PV from lp (this-iter data) and bv regs — unchanged
#pragma unroll
    for (int ks = 0; ks < 4; ks++)
#pragma unroll
      for (int mt = 0; mt < 4; mt++) {
        const int rp = mt * 16 + l16;
        const short8 ap = *(const short8*)&lp[rp * 128 + (((ks * 4 + quad) ^ (rp & 7)) * 8)];
        osc[mt] = mfma16x16x32(ap, bv[ks], osc[mt]);
      }
    __syncthreads();  // everyone done with lp; staging drains before next frag reads
  }

  // row-sum reduce: lane holds per-t partials over its s-share; fold quads.
#pragma unroll
  for (int tj = 0; tj < 4; tj++) {
    float v = lrow[tj];
    v += __shfl_xor(v, 16);
    v += __shfl_xor(v, 32);
    if (quad == 0) atomicAdd(&lsum[tj * 16 + l16], v);
  }
  __syncthreads();

  const long bh = bz * 8 + h;
  float* op = Opart + ((bh * NCH + ch) * 64) * 64 + w * 16 + l16;
#pragma unroll
  for (int mt = 0; mt < 4; mt++)
#pragma unroll
    for (int r = 0; r < 4; r++)
      op[(long)(mt * 16 + quad * 4 + r) * 64] = osc[mt][r];
  if (tid < 64) lpart[(bh * NCH + ch) * 64 + tid] = lsum[tid];
}

// ---------------- combine attention partials -> tmp bf16 (b,t,i) ----------------
// 4-wide vectorized (float4 reads of Opart, short4 writes of tmp).
__global__ __launch_bounds__(256) void attn_combine(
    const float* __restrict__ Opart, const float* __restrict__ lpart,
    short* __restrict__ tmp, int b0, int nbh) {
  const int total4 = nbh * 1024;  // groups of 4 consecutive d
  for (int i4 = blockIdx.x * 256 + threadIdx.x; i4 < total4;
       i4 += gridDim.x * 256) {
    const int bh = i4 >> 10;
    const int td = (i4 & 1023) << 2;  // multiple of 4; same t for all 4
    const int t = td >> 6;
    float4v o = (float4v)0.0f;
    float l = 0.0f;
#pragma unroll
    for (int c = 0; c < NCH; c++) {
      o += *(const float4v*)&Opart[(((long)bh * NCH + c) << 12) + td];
      l += lpart[(bh * NCH + c) * 64 + t];
    }
    const float inv = 1.0f / l;
    const int b = b0 + (bh >> 3), h = bh & 7;
    short4v r;
#pragma unroll
    for (int j = 0; j < 4; j++) r[j] = f2bf(o[j] * inv);
    *(short4v*)&tmp[((long)b * 64 + t) * 512 + h * 64 + (td & 63)] = r;
  }
}

// ---------------- launch ----------------
extern "C" void kernel_launch(void* const* d_in, const int* in_sizes, int n_in,
                              void* d_out, int out_size, void* d_ws, size_t ws_size,
                              hipStream_t stream) {
  (void)in_sizes; (void)n_in; (void)out_size;
  const float* vis = (const float*)d_in[0];   // [16][512][4096] fp32
  const float* lang = (const float*)d_in[1];  // [16][64][512]  fp32
  const float* Wq = (const float*)d_in[3];    // [512][512] fp32
  const float* Wk = (const float*)d_in[4];
  const float* Wv = (const float*)d_in[5];
  const float* Wo = (const float*)d_in[6];
  float* out = (float*)d_out;                 // [16][64][512] fp32

  char* ws = (char*)d_ws;
  const size_t MB = 1 << 20;
  short* q_ws = (short*)(ws + 0 * MB);
  short* tmp_ws = (short*)(ws + 1 * MB);
  short* langb = (short*)(ws + 2 * MB);
  short* Wqb = (short*)(ws + 3 * MB);
  short* Wkb = (short*)(ws + 3 * MB + 512 * 1024);
  short* Wvb = (short*)(ws + 4 * MB);
  short* Wob = (short*)(ws + 4 * MB + 512 * 1024);
  char* grp = ws + 5 * MB;

  const long batch_elems = 4096l * 512;   // bf16 elems per batch (k or v)
  const long vis_f32 = 512l * 4096;       // fp32 elems per batch of vis
  int g = 16;
  const int cands[5] = {1, 2, 4, 8, 16};
  for (int ci = 0; ci < 5; ci++) {
    const int Bgc = 16 / cands[ci];
    const size_t need = 5 * MB + 2ull * Bgc * batch_elems * 2       // k + v
                        + (size_t)Bgc * 8 * NCH * 4096 * 4          // Opart
                        + (size_t)Bgc * 8 * NCH * 64 * 4 + 4096;    // lpart
    if (need <= ws_size) { g = cands[ci]; break; }
  }
  const int Bg = 16 / g;
  short* k_ws = (short*)grp;                    // [Bg][4096][512] (s,i)
  short* v_ws = k_ws + (long)Bg * batch_elems;  // [Bg][512][4096] (i,s)
  float* Opart = (float*)(v_ws + (long)Bg * batch_elems);
  float* lptr = Opart + (long)Bg * 8 * NCH * 4096;

  convert5<<<dim3(128, 5), 256, 0, stream>>>(lang, langb, Wq, Wqb, Wk, Wkb,
                                             Wv, Wvb, Wo, Wob);

  // q = SCALE * lang @ Wq^T
  gemm_nt<0><<<dim3(4, 8), 256, 0, stream>>>(langb, Wqb, q_ws, 512, 512, 0.125f);

  for (int gi = 0; gi < g; gi++) {
    const int b0 = gi * Bg;
    gemm_kv<<<dim3(32, 4, Bg), 512, 0, stream>>>(Wkb, Wvb, vis + (long)b0 * vis_f32,
                                                 vis_f32, k_ws, v_ws, batch_elems);
    attn_part<<<dim3(8, Bg, NCH), 256, 0, stream>>>(q_ws, k_ws, v_ws, Opart, lptr, b0);
    attn_combine<<<512, 256, 0, stream>>>(Opart, lptr, tmp_ws, b0, Bg * 8);
  }

  // out = tmp @ Wo^T, fp32 epilogue
  gemm_nt<1><<<dim3(4, 8), 256, 0, stream>>>(tmp_ws, Wob, out, 512, 512, 1.0f);
}